// Round 2
// baseline (5085.226 us; speedup 1.0000x reference)
//
#include <hip/hip_runtime.h>
#include <math.h>

#define B_EV    16
#define N_NODES 2048
#define K_NN    16
#define F_IN    64
#define L_OUT   64
#define NT      (B_EV * N_NODES)      // 32768
#define EDGES   (NT * K_NN)           // 524288

// ---------------- K0: per-node squared norms, bit-exact numpy pairwise fp32 ----------------
// numpy pairwise_sum for n=64: r[j] = sum_{i=0..7} a[j+8i] (sequential fp32 adds),
// result = ((r0+r1)+(r2+r3)) + ((r4+r5)+(r6+r7)).
// 8 lanes per node; shfl_xor(1,2,4) tree reproduces the combine order exactly.
__global__ __launch_bounds__(256) void k_sq(const float* __restrict__ x,
                                            float* __restrict__ sq) {
  int tid = blockIdx.x * 256 + threadIdx.x;
  int node = tid >> 3;
  int j = tid & 7;
  const float* xr = x + (size_t)node * F_IN;
  float xv = xr[j];
  float s = __fmul_rn(xv, xv);
  #pragma unroll
  for (int i = 1; i < 8; ++i) {
    float c = xr[j + 8 * i];
    s = __fadd_rn(s, __fmul_rn(c, c));
  }
  s = __fadd_rn(s, __shfl_xor(s, 1));
  s = __fadd_rn(s, __shfl_xor(s, 2));
  s = __fadd_rn(s, __shfl_xor(s, 4));
  if (j == 0) sq[node] = s;
}

// ---------------- K1: u = x@(W1-W2), v = x@W2 ----------------
__global__ __launch_bounds__(256) void k_uv(const float* __restrict__ x,
                                            const float* __restrict__ W,
                                            float* __restrict__ u,
                                            float* __restrict__ v) {
  __shared__ float wd[64][65];
  __shared__ float w2[64][65];
  __shared__ float xs[16][64];
  for (int i = threadIdx.x; i < 4096; i += 256) {
    int f = i >> 6, l = i & 63;
    float w1v = W[i];           // W[f][l], f<64
    float w2v = W[4096 + i];    // W[64+f][l]
    wd[f][l] = w1v - w2v;
    w2[f][l] = w2v;
  }
  int nodeBase = blockIdx.x * 16;
  for (int i = threadIdx.x; i < 1024; i += 256) {
    xs[i >> 6][i & 63] = x[(size_t)nodeBase * 64 + i];
  }
  __syncthreads();
  int l = threadIdx.x & 63, g = threadIdx.x >> 6;
  #pragma unroll
  for (int rep = 0; rep < 4; ++rep) {
    int n = g * 4 + rep;
    float au = 0.f, av = 0.f;
    #pragma unroll
    for (int f = 0; f < 64; ++f) {
      float xv = xs[n][f];
      au = fmaf(xv, wd[f][l], au);
      av = fmaf(xv, w2[f][l], av);
    }
    u[(size_t)(nodeBase + n) * 64 + l] = au;
    v[(size_t)(nodeBase + n) * 64 + l] = av;
  }
}

// ---------------- K2: per-event kNN ----------------
// Stage 1: fast fp32 FMA scan keeps top-20 per 256-column chunk (slack vs noise).
// Stage 2: every thread rescores its own 20 candidates with numpy-emulated fp32:
//          s32 = fl32( fl32(sqn_np + sqm_np) - fl32(2 * fl32(dot64)) )
// Stage 3: 32 threads merge 160 scored candidates, stable top-16 on (s32, idx).
#define NCH    8
#define CHCOLS (N_NODES / NCH)   // 256
#define RB     32                // rows per block
#define NS     20                // scan slots per chunk
#define NC     (NCH * NS)        // 160 candidates per row
#define NCP    (NC + 1)          // LDS pad

__global__ void k_knn(const float* __restrict__ x,
                      const float* __restrict__ sq,
                      int* __restrict__ nidx) {
  __shared__ float scS[RB][NCP];
  __shared__ int   idS[RB][NCP];
  const int r  = threadIdx.x & (RB - 1);
  const int cg = threadIdx.x >> 5;       // 0..7 column chunk
  const int ev = blockIdx.x >> 6;        // 64 rowblocks per event
  const int rb = blockIdx.x & 63;
  const int row = ev * N_NODES + rb * RB + r;   // global node id
  const float* __restrict__ xev  = x + (size_t)ev * N_NODES * F_IN;
  const float* __restrict__ sqev = sq + ev * N_NODES;

  float4 xi[16];
  {
    const float4* xr = (const float4*)(x + (size_t)row * F_IN);
    #pragma unroll
    for (int fq = 0; fq < 16; ++fq) xi[fq] = xr[fq];
  }
  const float sqn = sqev[rb * RB + r];

  float dist[NS]; int idxk[NS];
  #pragma unroll
  for (int t = 0; t < NS; ++t) { dist[t] = 3.4e38f; idxk[t] = 0x7FFFFFFF; }
  float curMax = 3.4e38f;

  const int colBase = cg * CHCOLS;
  for (int m = 0; m < CHCOLS; ++m) {
    const int col = colBase + m;
    const float4* xc = (const float4*)(xev + (size_t)col * F_IN);
    float a0 = 0.f, a1 = 0.f, a2 = 0.f, a3 = 0.f;
    #pragma unroll
    for (int fq = 0; fq < 16; fq += 4) {
      float4 c0 = xc[fq + 0], c1 = xc[fq + 1], c2 = xc[fq + 2], c3 = xc[fq + 3];
      a0 = fmaf(xi[fq + 0].x, c0.x, a0);
      a0 = fmaf(xi[fq + 0].y, c0.y, a0);
      a0 = fmaf(xi[fq + 0].z, c0.z, a0);
      a0 = fmaf(xi[fq + 0].w, c0.w, a0);
      a1 = fmaf(xi[fq + 1].x, c1.x, a1);
      a1 = fmaf(xi[fq + 1].y, c1.y, a1);
      a1 = fmaf(xi[fq + 1].z, c1.z, a1);
      a1 = fmaf(xi[fq + 1].w, c1.w, a1);
      a2 = fmaf(xi[fq + 2].x, c2.x, a2);
      a2 = fmaf(xi[fq + 2].y, c2.y, a2);
      a2 = fmaf(xi[fq + 2].z, c2.z, a2);
      a2 = fmaf(xi[fq + 2].w, c2.w, a2);
      a3 = fmaf(xi[fq + 3].x, c3.x, a3);
      a3 = fmaf(xi[fq + 3].y, c3.y, a3);
      a3 = fmaf(xi[fq + 3].z, c3.z, a3);
      a3 = fmaf(xi[fq + 3].w, c3.w, a3);
    }
    const float s = sqev[col] - 2.0f * ((a0 + a1) + (a2 + a3));
    if (s < curMax) {
      float bv = dist[0]; int bi = idxk[0]; int slot = 0;
      #pragma unroll
      for (int t = 1; t < NS; ++t) {
        bool better = (dist[t] > bv) || ((dist[t] == bv) && (idxk[t] > bi));
        slot = better ? t : slot;
        bv = better ? dist[t] : bv;
        bi = better ? idxk[t] : bi;
      }
      #pragma unroll
      for (int t = 0; t < NS; ++t) {
        dist[t] = (t == slot) ? s : dist[t];
        idxk[t] = (t == slot) ? col : idxk[t];
      }
      curMax = dist[0];
      #pragma unroll
      for (int t = 1; t < NS; ++t) curMax = fmaxf(curMax, dist[t]);
    }
  }

  // numpy-fp32-emulated rescore of own candidates (dot in fp64, one rounding)
  #pragma unroll
  for (int t = 0; t < NS; ++t) {
    const int m = idxk[t];
    const float4* xm = (const float4*)(xev + (size_t)m * F_IN);
    double dot = 0.0;
    #pragma unroll
    for (int fq = 0; fq < 16; ++fq) {
      float4 cc = xm[fq];
      dot = fma((double)xi[fq].x, (double)cc.x, dot);
      dot = fma((double)xi[fq].y, (double)cc.y, dot);
      dot = fma((double)xi[fq].z, (double)cc.z, dot);
      dot = fma((double)xi[fq].w, (double)cc.w, dot);
    }
    const float dot32 = (float)dot;
    const float s32 = __fsub_rn(__fadd_rn(sqn, sqev[m]),
                                __fmul_rn(2.0f, dot32));
    scS[r][cg * NS + t] = s32;
    idS[r][cg * NS + t] = m;
  }
  __syncthreads();

  if (threadIdx.x < RB) {
    // stable top-16 on (s32, idx): ties keep lower index (jax.lax.top_k)
    float dd[K_NN]; int di[K_NN];
    #pragma unroll
    for (int t = 0; t < K_NN; ++t) { dd[t] = 3.4e38f; di[t] = 0x7FFFFFFF; }
    for (int c = 0; c < NC; ++c) {
      const float s = scS[r][c];
      const int m = idS[r][c];
      float bv = dd[0]; int bi = di[0]; int slot = 0;
      #pragma unroll
      for (int t = 1; t < K_NN; ++t) {
        bool worse = (dd[t] > bv) || ((dd[t] == bv) && (di[t] > bi));
        slot = worse ? t : slot;
        bv = worse ? dd[t] : bv;
        bi = worse ? di[t] : bi;
      }
      const bool take = (s < bv) || ((s == bv) && (m < bi));
      if (take) {
        #pragma unroll
        for (int t = 0; t < K_NN; ++t) {
          dd[t] = (t == slot) ? s : dd[t];
          di[t] = (t == slot) ? m : di[t];
        }
      }
    }
    #pragma unroll
    for (int t = 0; t < K_NN; ++t)
      nidx[(size_t)row * K_NN + t] = ev * N_NODES + di[t];
  }
}

// ---------------- K3: BN statistics over all edges ----------------
#define NB3 32
__global__ __launch_bounds__(256) void k_stats(const float* __restrict__ u,
                                               const float* __restrict__ v,
                                               const int* __restrict__ nidx,
                                               const float* __restrict__ bvec,
                                               float* __restrict__ stats) {
  __shared__ float red1[4][64];
  __shared__ float red2[4][64];
  const int l = threadIdx.x & 63, g = threadIdx.x >> 6;
  const int base = blockIdx.x * NB3;
  const float bl = bvec[l];
  float s1 = 0.f, s2 = 0.f;
  for (int nn = g; nn < NB3; nn += 4) {
    const int node = base + nn;
    const float ui = u[(size_t)node * 64 + l] + bl;
    const int* ip = nidx + (size_t)node * K_NN;
    #pragma unroll
    for (int k = 0; k < K_NN; ++k) {
      const float vj = v[(size_t)ip[k] * 64 + l];
      const float h = ui + vj;
      s1 += h;
      s2 = fmaf(h, h, s2);
    }
  }
  red1[g][l] = s1; red2[g][l] = s2;
  __syncthreads();
  if (g == 0) {
    float t1 = red1[0][l] + red1[1][l] + red1[2][l] + red1[3][l];
    float t2 = red2[0][l] + red2[1][l] + red2[2][l] + red2[3][l];
    atomicAdd(&stats[l], t1);
    atomicAdd(&stats[64 + l], t2);
  }
}

// ---------------- K4: normalize + relu + mean over K ----------------
__global__ __launch_bounds__(256) void k_out(const float* __restrict__ u,
                                             const float* __restrict__ v,
                                             const int* __restrict__ nidx,
                                             const float* __restrict__ bvec,
                                             const float* __restrict__ gamma,
                                             const float* __restrict__ beta,
                                             const float* __restrict__ stats,
                                             float* __restrict__ out) {
  const int l = threadIdx.x & 63, g = threadIdx.x >> 6;
  const float inv = 1.0f / (float)EDGES;
  const float mean = stats[l] * inv;
  const float ex2 = stats[64 + l] * inv;
  const float var = ex2 - mean * mean;   // biased variance, matches jnp.var
  const float a = gamma[l] * rsqrtf(var + 1e-5f);
  const float bb = fmaf(-mean, a, beta[l]);
  const float bl = bvec[l];
  const int base = blockIdx.x * NB3;
  for (int nn = g; nn < NB3; nn += 4) {
    const int node = base + nn;
    const float ui = u[(size_t)node * 64 + l] + bl;
    const int* ip = nidx + (size_t)node * K_NN;
    float acc = 0.f;
    #pragma unroll
    for (int k = 0; k < K_NN; ++k) {
      const float vj = v[(size_t)ip[k] * 64 + l];
      const float h = ui + vj;
      acc += fmaxf(fmaf(a, h, bb), 0.f);
    }
    out[(size_t)node * 64 + l] = acc * (1.0f / 16.0f);
  }
}

// ---------------- launcher ----------------
extern "C" void kernel_launch(void* const* d_in, const int* in_sizes, int n_in,
                              void* d_out, int out_size, void* d_ws, size_t ws_size,
                              hipStream_t stream) {
  (void)in_sizes; (void)n_in; (void)out_size; (void)ws_size;
  const float* x     = (const float*)d_in[0];
  // d_in[1] = batch (equal-size events; layout known statically) - unused
  const float* W     = (const float*)d_in[2];
  const float* b     = (const float*)d_in[3];
  const float* gamma = (const float*)d_in[4];
  const float* beta  = (const float*)d_in[5];
  float* out = (float*)d_out;

  char* ws = (char*)d_ws;
  float* u     = (float*)(ws);                    //  8 MB
  float* v     = (float*)(ws + 8388608);          //  8 MB
  float* sq    = (float*)(ws + 16777216);         //  128 KB
  int*   nidx  = (int*)  (ws + 16908288);         //  2 MB
  float* stats = (float*)(ws + 19005440);         //  512 B

  hipMemsetAsync(stats, 0, 512, stream);
  k_sq  <<<1024, 256, 0, stream>>>(x, sq);
  k_uv  <<<2048, 256, 0, stream>>>(x, W, u, v);
  k_knn <<<1024, 256, 0, stream>>>(x, sq, nidx);
  k_stats<<<1024, 256, 0, stream>>>(u, v, nidx, b, stats);
  k_out <<<1024, 256, 0, stream>>>(u, v, nidx, b, gamma, beta, stats, out);
}

// Round 3
// 1526.506 us; speedup vs baseline: 3.3313x; 3.3313x over previous
//
#include <hip/hip_runtime.h>
#include <math.h>

#define B_EV    16
#define N_NODES 2048
#define K_NN    16
#define F_IN    64
#define L_OUT   64
#define NT      (B_EV * N_NODES)      // 32768
#define EDGES   (NT * K_NN)           // 524288

// ---------------- K0: per-node squared norms, bit-exact numpy pairwise fp32 ----------------
// numpy pairwise_sum for n=64: r[j] = sum_{i=0..7} a[j+8i] (sequential fp32 adds),
// result = ((r0+r1)+(r2+r3)) + ((r4+r5)+(r6+r7)).
// 8 lanes per node; shfl_xor(1,2,4) tree reproduces the combine order exactly.
__global__ __launch_bounds__(256) void k_sq(const float* __restrict__ x,
                                            float* __restrict__ sq) {
  int tid = blockIdx.x * 256 + threadIdx.x;
  int node = tid >> 3;
  int j = tid & 7;
  const float* xr = x + (size_t)node * F_IN;
  float xv = xr[j];
  float s = __fmul_rn(xv, xv);
  #pragma unroll
  for (int i = 1; i < 8; ++i) {
    float c = xr[j + 8 * i];
    s = __fadd_rn(s, __fmul_rn(c, c));
  }
  s = __fadd_rn(s, __shfl_xor(s, 1));
  s = __fadd_rn(s, __shfl_xor(s, 2));
  s = __fadd_rn(s, __shfl_xor(s, 4));
  if (j == 0) sq[node] = s;
}

// ---------------- K1: u = x@(W1-W2), v = x@W2 ----------------
__global__ __launch_bounds__(256) void k_uv(const float* __restrict__ x,
                                            const float* __restrict__ W,
                                            float* __restrict__ u,
                                            float* __restrict__ v) {
  __shared__ float wd[64][65];
  __shared__ float w2[64][65];
  __shared__ float xs[16][64];
  for (int i = threadIdx.x; i < 4096; i += 256) {
    int f = i >> 6, l = i & 63;
    float w1v = W[i];           // W[f][l], f<64
    float w2v = W[4096 + i];    // W[64+f][l]
    wd[f][l] = w1v - w2v;
    w2[f][l] = w2v;
  }
  int nodeBase = blockIdx.x * 16;
  for (int i = threadIdx.x; i < 1024; i += 256) {
    xs[i >> 6][i & 63] = x[(size_t)nodeBase * 64 + i];
  }
  __syncthreads();
  int l = threadIdx.x & 63, g = threadIdx.x >> 6;
  #pragma unroll
  for (int rep = 0; rep < 4; ++rep) {
    int n = g * 4 + rep;
    float au = 0.f, av = 0.f;
    #pragma unroll
    for (int f = 0; f < 64; ++f) {
      float xv = xs[n][f];
      au = fmaf(xv, wd[f][l], au);
      av = fmaf(xv, w2[f][l], av);
    }
    u[(size_t)(nodeBase + n) * 64 + l] = au;
    v[(size_t)(nodeBase + n) * 64 + l] = av;
  }
}

// ---------------- K2: per-event kNN ----------------
// Stage 1: fast fp32 FMA scan keeps top-20 per 256-column chunk (slack vs noise).
// Stage 2: every thread rescores its own 20 candidates with numpy-emulated fp32:
//          s32 = fl32( fl32(sqn_np + sqm_np) - fl32(2 * fl32(dot64)) )
// Stage 3: 32 threads merge 160 scored candidates, stable top-16 on (s32, idx).
#define NCH    8
#define CHCOLS (N_NODES / NCH)   // 256
#define RB     32                // rows per block
#define NS     20                // scan slots per chunk
#define NC     (NCH * NS)        // 160 candidates per row
#define NCP    (NC + 1)          // LDS pad

__global__ __launch_bounds__(256, 1) void k_knn(const float* __restrict__ x,
                                                const float* __restrict__ sq,
                                                int* __restrict__ nidx) {
  __shared__ float scS[RB][NCP];
  __shared__ int   idS[RB][NCP];
  const int r  = threadIdx.x & (RB - 1);
  const int cg = threadIdx.x >> 5;       // 0..7 column chunk
  const int ev = blockIdx.x >> 6;        // 64 rowblocks per event
  const int rb = blockIdx.x & 63;
  const int row = ev * N_NODES + rb * RB + r;   // global node id
  const float* __restrict__ xev  = x + (size_t)ev * N_NODES * F_IN;
  const float* __restrict__ sqev = sq + ev * N_NODES;

  float4 xi[16];
  {
    const float4* xr = (const float4*)(x + (size_t)row * F_IN);
    #pragma unroll
    for (int fq = 0; fq < 16; ++fq) xi[fq] = xr[fq];
  }
  const float sqn = sqev[rb * RB + r];

  float dist[NS]; int idxk[NS];
  #pragma unroll
  for (int t = 0; t < NS; ++t) { dist[t] = 3.4e38f; idxk[t] = 0x7FFFFFFF; }
  float curMax = 3.4e38f;

  const int colBase = cg * CHCOLS;
  for (int m = 0; m < CHCOLS; ++m) {
    const int col = colBase + m;
    const float4* xc = (const float4*)(xev + (size_t)col * F_IN);
    float a0 = 0.f, a1 = 0.f, a2 = 0.f, a3 = 0.f;
    #pragma unroll
    for (int fq = 0; fq < 16; fq += 4) {
      float4 c0 = xc[fq + 0], c1 = xc[fq + 1], c2 = xc[fq + 2], c3 = xc[fq + 3];
      a0 = fmaf(xi[fq + 0].x, c0.x, a0);
      a0 = fmaf(xi[fq + 0].y, c0.y, a0);
      a0 = fmaf(xi[fq + 0].z, c0.z, a0);
      a0 = fmaf(xi[fq + 0].w, c0.w, a0);
      a1 = fmaf(xi[fq + 1].x, c1.x, a1);
      a1 = fmaf(xi[fq + 1].y, c1.y, a1);
      a1 = fmaf(xi[fq + 1].z, c1.z, a1);
      a1 = fmaf(xi[fq + 1].w, c1.w, a1);
      a2 = fmaf(xi[fq + 2].x, c2.x, a2);
      a2 = fmaf(xi[fq + 2].y, c2.y, a2);
      a2 = fmaf(xi[fq + 2].z, c2.z, a2);
      a2 = fmaf(xi[fq + 2].w, c2.w, a2);
      a3 = fmaf(xi[fq + 3].x, c3.x, a3);
      a3 = fmaf(xi[fq + 3].y, c3.y, a3);
      a3 = fmaf(xi[fq + 3].z, c3.z, a3);
      a3 = fmaf(xi[fq + 3].w, c3.w, a3);
    }
    const float s = sqev[col] - 2.0f * ((a0 + a1) + (a2 + a3));
    if (s < curMax) {
      float bv = dist[0]; int bi = idxk[0]; int slot = 0;
      #pragma unroll
      for (int t = 1; t < NS; ++t) {
        bool better = (dist[t] > bv) || ((dist[t] == bv) && (idxk[t] > bi));
        slot = better ? t : slot;
        bv = better ? dist[t] : bv;
        bi = better ? idxk[t] : bi;
      }
      #pragma unroll
      for (int t = 0; t < NS; ++t) {
        dist[t] = (t == slot) ? s : dist[t];
        idxk[t] = (t == slot) ? col : idxk[t];
      }
      curMax = dist[0];
      #pragma unroll
      for (int t = 1; t < NS; ++t) curMax = fmaxf(curMax, dist[t]);
    }
  }

  // numpy-fp32-emulated rescore of own candidates (dot in fp64, one rounding)
  #pragma unroll
  for (int t = 0; t < NS; ++t) {
    const int m = idxk[t];
    const float4* xm = (const float4*)(xev + (size_t)m * F_IN);
    double dot = 0.0;
    #pragma unroll
    for (int fq = 0; fq < 16; ++fq) {
      float4 cc = xm[fq];
      dot = fma((double)xi[fq].x, (double)cc.x, dot);
      dot = fma((double)xi[fq].y, (double)cc.y, dot);
      dot = fma((double)xi[fq].z, (double)cc.z, dot);
      dot = fma((double)xi[fq].w, (double)cc.w, dot);
    }
    const float dot32 = (float)dot;
    const float s32 = __fsub_rn(__fadd_rn(sqn, sqev[m]),
                                __fmul_rn(2.0f, dot32));
    scS[r][cg * NS + t] = s32;
    idS[r][cg * NS + t] = m;
  }
  __syncthreads();

  if (threadIdx.x < RB) {
    // stable top-16 on (s32, idx): ties keep lower index (jax.lax.top_k)
    float dd[K_NN]; int di[K_NN];
    #pragma unroll
    for (int t = 0; t < K_NN; ++t) { dd[t] = 3.4e38f; di[t] = 0x7FFFFFFF; }
    for (int c = 0; c < NC; ++c) {
      const float s = scS[r][c];
      const int m = idS[r][c];
      float bv = dd[0]; int bi = di[0]; int slot = 0;
      #pragma unroll
      for (int t = 1; t < K_NN; ++t) {
        bool worse = (dd[t] > bv) || ((dd[t] == bv) && (di[t] > bi));
        slot = worse ? t : slot;
        bv = worse ? dd[t] : bv;
        bi = worse ? di[t] : bi;
      }
      const bool take = (s < bv) || ((s == bv) && (m < bi));
      if (take) {
        #pragma unroll
        for (int t = 0; t < K_NN; ++t) {
          dd[t] = (t == slot) ? s : dd[t];
          di[t] = (t == slot) ? m : di[t];
        }
      }
    }
    #pragma unroll
    for (int t = 0; t < K_NN; ++t)
      nidx[(size_t)row * K_NN + t] = ev * N_NODES + di[t];
  }
}

// ---------------- K3: BN statistics over all edges ----------------
#define NB3 32
__global__ __launch_bounds__(256) void k_stats(const float* __restrict__ u,
                                               const float* __restrict__ v,
                                               const int* __restrict__ nidx,
                                               const float* __restrict__ bvec,
                                               float* __restrict__ stats) {
  __shared__ float red1[4][64];
  __shared__ float red2[4][64];
  const int l = threadIdx.x & 63, g = threadIdx.x >> 6;
  const int base = blockIdx.x * NB3;
  const float bl = bvec[l];
  float s1 = 0.f, s2 = 0.f;
  for (int nn = g; nn < NB3; nn += 4) {
    const int node = base + nn;
    const float ui = u[(size_t)node * 64 + l] + bl;
    const int* ip = nidx + (size_t)node * K_NN;
    #pragma unroll
    for (int k = 0; k < K_NN; ++k) {
      const float vj = v[(size_t)ip[k] * 64 + l];
      const float h = ui + vj;
      s1 += h;
      s2 = fmaf(h, h, s2);
    }
  }
  red1[g][l] = s1; red2[g][l] = s2;
  __syncthreads();
  if (g == 0) {
    float t1 = red1[0][l] + red1[1][l] + red1[2][l] + red1[3][l];
    float t2 = red2[0][l] + red2[1][l] + red2[2][l] + red2[3][l];
    atomicAdd(&stats[l], t1);
    atomicAdd(&stats[64 + l], t2);
  }
}

// ---------------- K4: normalize + relu + mean over K ----------------
__global__ __launch_bounds__(256) void k_out(const float* __restrict__ u,
                                             const float* __restrict__ v,
                                             const int* __restrict__ nidx,
                                             const float* __restrict__ bvec,
                                             const float* __restrict__ gamma,
                                             const float* __restrict__ beta,
                                             const float* __restrict__ stats,
                                             float* __restrict__ out) {
  const int l = threadIdx.x & 63, g = threadIdx.x >> 6;
  const float inv = 1.0f / (float)EDGES;
  const float mean = stats[l] * inv;
  const float ex2 = stats[64 + l] * inv;
  const float var = ex2 - mean * mean;   // biased variance, matches jnp.var
  const float a = gamma[l] * rsqrtf(var + 1e-5f);
  const float bb = fmaf(-mean, a, beta[l]);
  const float bl = bvec[l];
  const int base = blockIdx.x * NB3;
  for (int nn = g; nn < NB3; nn += 4) {
    const int node = base + nn;
    const float ui = u[(size_t)node * 64 + l] + bl;
    const int* ip = nidx + (size_t)node * K_NN;
    float acc = 0.f;
    #pragma unroll
    for (int k = 0; k < K_NN; ++k) {
      const float vj = v[(size_t)ip[k] * 64 + l];
      const float h = ui + vj;
      acc += fmaxf(fmaf(a, h, bb), 0.f);
    }
    out[(size_t)node * 64 + l] = acc * (1.0f / 16.0f);
  }
}

// ---------------- launcher ----------------
extern "C" void kernel_launch(void* const* d_in, const int* in_sizes, int n_in,
                              void* d_out, int out_size, void* d_ws, size_t ws_size,
                              hipStream_t stream) {
  (void)in_sizes; (void)n_in; (void)out_size; (void)ws_size;
  const float* x     = (const float*)d_in[0];
  // d_in[1] = batch (equal-size events; layout known statically) - unused
  const float* W     = (const float*)d_in[2];
  const float* b     = (const float*)d_in[3];
  const float* gamma = (const float*)d_in[4];
  const float* beta  = (const float*)d_in[5];
  float* out = (float*)d_out;

  char* ws = (char*)d_ws;
  float* u     = (float*)(ws);                    //  8 MB
  float* v     = (float*)(ws + 8388608);          //  8 MB
  float* sq    = (float*)(ws + 16777216);         //  128 KB
  int*   nidx  = (int*)  (ws + 16908288);         //  2 MB
  float* stats = (float*)(ws + 19005440);         //  512 B

  hipMemsetAsync(stats, 0, 512, stream);
  k_sq  <<<1024, 256, 0, stream>>>(x, sq);
  k_uv  <<<2048, 256, 0, stream>>>(x, W, u, v);
  k_knn <<<1024, 256, 0, stream>>>(x, sq, nidx);
  k_stats<<<1024, 256, 0, stream>>>(u, v, nidx, b, stats);
  k_out <<<1024, 256, 0, stream>>>(u, v, nidx, b, gamma, beta, stats, out);
}

// Round 4
// 1077.871 us; speedup vs baseline: 4.7178x; 1.4162x over previous
//
#include <hip/hip_runtime.h>
#include <math.h>

#define B_EV    16
#define N_NODES 2048
#define K_NN    16
#define F_IN    64
#define L_OUT   64
#define NT      (B_EV * N_NODES)      // 32768
#define EDGES   (NT * K_NN)           // 524288

typedef __attribute__((ext_vector_type(8)))  short bh8;    // 8 bf16 = 4 VGPR
typedef __attribute__((ext_vector_type(16))) float f32x16; // MFMA acc

// ---------------- K0: per-node squared norms, bit-exact numpy pairwise fp32 ----------------
__global__ __launch_bounds__(256) void k_sq(const float* __restrict__ x,
                                            float* __restrict__ sq) {
  int tid = blockIdx.x * 256 + threadIdx.x;
  int node = tid >> 3;
  int j = tid & 7;
  const float* xr = x + (size_t)node * F_IN;
  float xv = xr[j];
  float s = __fmul_rn(xv, xv);
  #pragma unroll
  for (int i = 1; i < 8; ++i) {
    float c = xr[j + 8 * i];
    s = __fadd_rn(s, __fmul_rn(c, c));
  }
  s = __fadd_rn(s, __shfl_xor(s, 1));
  s = __fadd_rn(s, __shfl_xor(s, 2));
  s = __fadd_rn(s, __shfl_xor(s, 4));
  if (j == 0) sq[node] = s;
}

// ---------------- K0b: split x into bf16 hi/lo (x = hi + lo) ----------------
__device__ inline unsigned short bf16_rne(float f) {
  unsigned int u = __float_as_uint(f);
  return (unsigned short)((u + 0x7FFFu + ((u >> 16) & 1u)) >> 16);
}
__device__ inline float bf16f(unsigned short h) {
  return __uint_as_float(((unsigned int)h) << 16);
}
__global__ __launch_bounds__(256) void k_cvt(const float* __restrict__ x,
                                             unsigned short* __restrict__ xh,
                                             unsigned short* __restrict__ xl) {
  int i = blockIdx.x * 256 + threadIdx.x;   // one float4 per thread
  float4 v = ((const float4*)x)[i];
  ushort4 h, l;
  h.x = bf16_rne(v.x); l.x = bf16_rne(v.x - bf16f(h.x));
  h.y = bf16_rne(v.y); l.y = bf16_rne(v.y - bf16f(h.y));
  h.z = bf16_rne(v.z); l.z = bf16_rne(v.z - bf16f(h.z));
  h.w = bf16_rne(v.w); l.w = bf16_rne(v.w - bf16f(h.w));
  ((ushort4*)xh)[i] = h;
  ((ushort4*)xl)[i] = l;
}

// ---------------- K1: u = x@(W1-W2), v = x@W2 ----------------
__global__ __launch_bounds__(256) void k_uv(const float* __restrict__ x,
                                            const float* __restrict__ W,
                                            float* __restrict__ u,
                                            float* __restrict__ v) {
  __shared__ float wd[64][65];
  __shared__ float w2[64][65];
  __shared__ float xs[16][64];
  for (int i = threadIdx.x; i < 4096; i += 256) {
    int f = i >> 6, l = i & 63;
    float w1v = W[i];
    float w2v = W[4096 + i];
    wd[f][l] = w1v - w2v;
    w2[f][l] = w2v;
  }
  int nodeBase = blockIdx.x * 16;
  for (int i = threadIdx.x; i < 1024; i += 256) {
    xs[i >> 6][i & 63] = x[(size_t)nodeBase * 64 + i];
  }
  __syncthreads();
  int l = threadIdx.x & 63, g = threadIdx.x >> 6;
  #pragma unroll
  for (int rep = 0; rep < 4; ++rep) {
    int n = g * 4 + rep;
    float au = 0.f, av = 0.f;
    #pragma unroll
    for (int f = 0; f < 64; ++f) {
      float xv = xs[n][f];
      au = fmaf(xv, wd[f][l], au);
      av = fmaf(xv, w2[f][l], av);
    }
    u[(size_t)(nodeBase + n) * 64 + l] = au;
    v[(size_t)(nodeBase + n) * 64 + l] = av;
  }
}

// ---------------- K2: per-event kNN via MFMA ----------------
// Block: 32 rows of one event, 256 threads (4 waves). 16 col-tiles of 128.
// Per tile: stage bf16 hi/lo cols -> LDS (XOR swizzle), each wave MFMAs its
// 32-col subtile (3 passes hh/hl/lh), writes s = sq[col]-2*dot into S LDS;
// 8 threads/row scan-select private top-16 candidates.
// Epilogue: merge 128 -> 24 by scan score, numpy-fp32-emulated rescore of 24,
// stable top-16 on (s32, idx).
#define NS 16
#define NC 128   // 8 thread-groups x NS

union KnnSmem {
  struct {
    char  xb[32768];      // [0]=hi tile, [16384]=lo tile: [128 cols][64 feat] bf16, swizzled
    float S[32 * 129];    // s-values, stride 129 (conflict-free)
  } a;
  struct {
    float sc[32][NC + 1];
    int   id[32][NC + 1];
    int   cand[32][24];
    float resc[32][24];
  } b;
};

__global__ __launch_bounds__(256, 3) void k_knn(const float* __restrict__ x,
                                                const unsigned short* __restrict__ xh,
                                                const unsigned short* __restrict__ xl,
                                                const float* __restrict__ sq,
                                                int* __restrict__ nidx) {
  __shared__ KnnSmem sm;
  const int t    = threadIdx.x;
  const int r    = t & 31;        // selection row
  const int c8   = t >> 5;        // selection col-group 0..7
  const int w    = t >> 6;        // wave 0..3
  const int lane = t & 63;
  const int ev    = blockIdx.x >> 6;
  const int strip = blockIdx.x & 63;
  const int rowBase = strip * 32;               // within event
  const size_t evNode = (size_t)ev * N_NODES;
  const float* __restrict__ sqev = sq + evNode;

  // ---- stage A (32 strip rows, hi+lo) and load A-frags ----
  {
    int col = t >> 3;                 // 0..31
    int fb  = (t & 7) << 4;           // byte within 128B row
    const char* gh = (const char*)(xh + (evNode + rowBase + col) * 64) + fb;
    const char* gl = (const char*)(xl + (evNode + rowBase + col) * 64) + fb;
    int off = (col * 128 + fb) ^ ((col & 7) << 4);
    *(uint4*)(sm.a.xb + off)         = *(const uint4*)gh;
    *(uint4*)(sm.a.xb + 16384 + off) = *(const uint4*)gl;
  }
  __syncthreads();
  bh8 ah[4], al[4];
  {
    int row = lane & 31;
    int fb  = (lane >> 5) * 16;       // 8 bf16 = 16 B per k-half
    #pragma unroll
    for (int ks = 0; ks < 4; ++ks) {
      int off = (row * 128 + ks * 32 + fb) ^ ((row & 7) << 4);
      ah[ks] = *(const bh8*)(sm.a.xb + off);
      al[ks] = *(const bh8*)(sm.a.xb + 16384 + off);
    }
  }

  float dist[NS]; int idxk[NS];
  #pragma unroll
  for (int q = 0; q < NS; ++q) { dist[q] = 3.4e38f; idxk[q] = 0x7FFFFFFF; }
  float curMax = 3.4e38f;

  for (int T = 0; T < 16; ++T) {
    __syncthreads();   // prev selection done; xb/S free (A-frags already in regs)
    const int tileCol = T * 128;
    // ---- stage B tile (128 cols, hi then lo) ----
    #pragma unroll
    for (int p = 0; p < 8; ++p) {
      int idx16 = (p & 3) * 256 + t;          // 16B-unit index in 16KB tile
      int col = idx16 >> 3;
      int fb  = (idx16 & 7) << 4;
      const unsigned short* src = (p < 4) ? xh : xl;
      const char* g = (const char*)(src + (evNode + tileCol + col) * 64) + fb;
      int off = ((p < 4) ? 0 : 16384) + ((col * 128 + fb) ^ ((col & 7) << 4));
      *(uint4*)(sm.a.xb + off) = *(const uint4*)g;
    }
    __syncthreads();
    // ---- MFMA: wave w -> cols [w*32, w*32+32) ----
    {
      f32x16 acc;
      #pragma unroll
      for (int q = 0; q < 16; ++q) acc[q] = 0.f;
      int colIn = w * 32 + (lane & 31);
      int fb = (lane >> 5) * 16;
      #pragma unroll
      for (int ks = 0; ks < 4; ++ks) {
        int off = (colIn * 128 + ks * 32 + fb) ^ ((colIn & 7) << 4);
        bh8 bh = *(const bh8*)(sm.a.xb + off);
        bh8 bl = *(const bh8*)(sm.a.xb + 16384 + off);
        acc = __builtin_amdgcn_mfma_f32_32x32x16_bf16(ah[ks], bh, acc, 0, 0, 0);
        acc = __builtin_amdgcn_mfma_f32_32x32x16_bf16(ah[ks], bl, acc, 0, 0, 0);
        acc = __builtin_amdgcn_mfma_f32_32x32x16_bf16(al[ks], bh, acc, 0, 0, 0);
      }
      float sqc = sqev[tileCol + colIn];
      #pragma unroll
      for (int reg = 0; reg < 16; ++reg) {
        int m = (reg & 3) + 8 * (reg >> 2) + 4 * (lane >> 5);
        sm.a.S[m * 129 + colIn] = fmaf(-2.0f, acc[reg], sqc);
      }
    }
    __syncthreads();
    // ---- selection: thread (r,c8) scans 16 cols ----
    for (int j = 0; j < 16; ++j) {
      int cIn = c8 * 16 + j;
      float s = sm.a.S[r * 129 + cIn];
      if (s <= curMax) {
        int col = tileCol + cIn;
        float bv = dist[0]; int bi = idxk[0]; int slot = 0;
        #pragma unroll
        for (int q = 1; q < NS; ++q) {
          bool worse = (dist[q] > bv) || ((dist[q] == bv) && (idxk[q] > bi));
          slot = worse ? q : slot;
          bv = worse ? dist[q] : bv;
          bi = worse ? idxk[q] : bi;
        }
        if ((s < bv) || ((s == bv) && (col < bi))) {
          #pragma unroll
          for (int q = 0; q < NS; ++q) {
            dist[q] = (q == slot) ? s : dist[q];
            idxk[q] = (q == slot) ? col : idxk[q];
          }
          float cm = dist[0];
          #pragma unroll
          for (int q = 1; q < NS; ++q) cm = fmaxf(cm, dist[q]);
          curMax = cm;
        }
      }
    }
  }

  __syncthreads();   // S reads done; switch LDS to union b
  #pragma unroll
  for (int q = 0; q < NS; ++q) {
    sm.b.sc[r][c8 * NS + q] = dist[q];
    sm.b.id[r][c8 * NS + q] = idxk[q];
  }
  __syncthreads();

  // ---- approx merge: 128 -> 24 by (scan score, idx) ----
  if (t < 32) {
    float dd[24]; int di[24];
    #pragma unroll
    for (int q = 0; q < 24; ++q) { dd[q] = 3.4e38f; di[q] = 0x7FFFFFFF; }
    for (int c = 0; c < NC; ++c) {
      float s = sm.b.sc[t][c];
      int m = sm.b.id[t][c];
      float bv = dd[0]; int bi = di[0]; int slot = 0;
      #pragma unroll
      for (int q = 1; q < 24; ++q) {
        bool worse = (dd[q] > bv) || ((dd[q] == bv) && (di[q] > bi));
        slot = worse ? q : slot;
        bv = worse ? dd[q] : bv;
        bi = worse ? di[q] : bi;
      }
      if ((s < bv) || ((s == bv) && (m < bi))) {
        #pragma unroll
        for (int q = 0; q < 24; ++q) {
          dd[q] = (q == slot) ? s : dd[q];
          di[q] = (q == slot) ? m : di[q];
        }
      }
    }
    #pragma unroll
    for (int q = 0; q < 24; ++q) sm.b.cand[t][q] = di[q];
  }
  __syncthreads();

  // ---- distributed numpy-fp32-emulated rescore: 3 candidates per thread ----
  {
    float4 xi[16];
    const float4* xr = (const float4*)(x + (evNode + rowBase + r) * F_IN);
    #pragma unroll
    for (int fq = 0; fq < 16; ++fq) xi[fq] = xr[fq];
    const float sqn = sqev[rowBase + r];
    const float* __restrict__ xev = x + evNode * F_IN;
    #pragma unroll
    for (int ii = 0; ii < 3; ++ii) {
      int i = c8 + ii * 8;
      int m = sm.b.cand[r][i];
      const float4* xm = (const float4*)(xev + (size_t)m * F_IN);
      double dot = 0.0;
      #pragma unroll
      for (int fq = 0; fq < 16; ++fq) {
        float4 cc = xm[fq];
        dot = fma((double)xi[fq].x, (double)cc.x, dot);
        dot = fma((double)xi[fq].y, (double)cc.y, dot);
        dot = fma((double)xi[fq].z, (double)cc.z, dot);
        dot = fma((double)xi[fq].w, (double)cc.w, dot);
      }
      const float dot32 = (float)dot;
      sm.b.resc[r][i] = __fsub_rn(__fadd_rn(sqn, sqev[m]),
                                  __fmul_rn(2.0f, dot32));
    }
  }
  __syncthreads();

  // ---- final stable top-16 on (s32, idx) over 24 rescored candidates ----
  if (t < 32) {
    float dd[K_NN]; int di[K_NN];
    #pragma unroll
    for (int q = 0; q < K_NN; ++q) { dd[q] = 3.4e38f; di[q] = 0x7FFFFFFF; }
    for (int c = 0; c < 24; ++c) {
      float s = sm.b.resc[t][c];
      int m = sm.b.cand[t][c];
      float bv = dd[0]; int bi = di[0]; int slot = 0;
      #pragma unroll
      for (int q = 1; q < K_NN; ++q) {
        bool worse = (dd[q] > bv) || ((dd[q] == bv) && (di[q] > bi));
        slot = worse ? q : slot;
        bv = worse ? dd[q] : bv;
        bi = worse ? di[q] : bi;
      }
      if ((s < bv) || ((s == bv) && (m < bi))) {
        #pragma unroll
        for (int q = 0; q < K_NN; ++q) {
          dd[q] = (q == slot) ? s : dd[q];
          di[q] = (q == slot) ? m : di[q];
        }
      }
    }
    const size_t row = evNode + rowBase + t;
    #pragma unroll
    for (int q = 0; q < K_NN; ++q)
      nidx[row * K_NN + q] = (int)evNode + di[q];
  }
}

// ---------------- K3: BN statistics over all edges ----------------
#define NB3 32
__global__ __launch_bounds__(256) void k_stats(const float* __restrict__ u,
                                               const float* __restrict__ v,
                                               const int* __restrict__ nidx,
                                               const float* __restrict__ bvec,
                                               float* __restrict__ stats) {
  __shared__ float red1[4][64];
  __shared__ float red2[4][64];
  const int l = threadIdx.x & 63, g = threadIdx.x >> 6;
  const int base = blockIdx.x * NB3;
  const float bl = bvec[l];
  float s1 = 0.f, s2 = 0.f;
  for (int nn = g; nn < NB3; nn += 4) {
    const int node = base + nn;
    const float ui = u[(size_t)node * 64 + l] + bl;
    const int* ip = nidx + (size_t)node * K_NN;
    #pragma unroll
    for (int k = 0; k < K_NN; ++k) {
      const float vj = v[(size_t)ip[k] * 64 + l];
      const float h = ui + vj;
      s1 += h;
      s2 = fmaf(h, h, s2);
    }
  }
  red1[g][l] = s1; red2[g][l] = s2;
  __syncthreads();
  if (g == 0) {
    float t1 = red1[0][l] + red1[1][l] + red1[2][l] + red1[3][l];
    float t2 = red2[0][l] + red2[1][l] + red2[2][l] + red2[3][l];
    atomicAdd(&stats[l], t1);
    atomicAdd(&stats[64 + l], t2);
  }
}

// ---------------- K4: normalize + relu + mean over K ----------------
__global__ __launch_bounds__(256) void k_out(const float* __restrict__ u,
                                             const float* __restrict__ v,
                                             const int* __restrict__ nidx,
                                             const float* __restrict__ bvec,
                                             const float* __restrict__ gamma,
                                             const float* __restrict__ beta,
                                             const float* __restrict__ stats,
                                             float* __restrict__ out) {
  const int l = threadIdx.x & 63, g = threadIdx.x >> 6;
  const float inv = 1.0f / (float)EDGES;
  const float mean = stats[l] * inv;
  const float ex2 = stats[64 + l] * inv;
  const float var = ex2 - mean * mean;
  const float a = gamma[l] * rsqrtf(var + 1e-5f);
  const float bb = fmaf(-mean, a, beta[l]);
  const float bl = bvec[l];
  const int base = blockIdx.x * NB3;
  for (int nn = g; nn < NB3; nn += 4) {
    const int node = base + nn;
    const float ui = u[(size_t)node * 64 + l] + bl;
    const int* ip = nidx + (size_t)node * K_NN;
    float acc = 0.f;
    #pragma unroll
    for (int k = 0; k < K_NN; ++k) {
      const float vj = v[(size_t)ip[k] * 64 + l];
      const float h = ui + vj;
      acc += fmaxf(fmaf(a, h, bb), 0.f);
    }
    out[(size_t)node * 64 + l] = acc * (1.0f / 16.0f);
  }
}

// ---------------- launcher ----------------
extern "C" void kernel_launch(void* const* d_in, const int* in_sizes, int n_in,
                              void* d_out, int out_size, void* d_ws, size_t ws_size,
                              hipStream_t stream) {
  (void)in_sizes; (void)n_in; (void)out_size; (void)ws_size;
  const float* x     = (const float*)d_in[0];
  const float* W     = (const float*)d_in[2];
  const float* b     = (const float*)d_in[3];
  const float* gamma = (const float*)d_in[4];
  const float* beta  = (const float*)d_in[5];
  float* out = (float*)d_out;

  char* ws = (char*)d_ws;
  float*          u     = (float*)(ws);                    //  8 MB
  float*          v     = (float*)(ws + 8388608);          //  8 MB
  float*          sq    = (float*)(ws + 16777216);         //  128 KB
  int*            nidx  = (int*)  (ws + 16908288);         //  2 MB
  float*          stats = (float*)(ws + 19005440);         //  512 B
  unsigned short* xh    = (unsigned short*)(ws + 19005952);//  4 MB
  unsigned short* xl    = (unsigned short*)(ws + 23200256);//  4 MB

  hipMemsetAsync(stats, 0, 512, stream);
  k_sq  <<<1024, 256, 0, stream>>>(x, sq);
  k_cvt <<<2048, 256, 0, stream>>>(x, xh, xl);
  k_uv  <<<2048, 256, 0, stream>>>(x, W, u, v);
  k_knn <<<1024, 256, 0, stream>>>(x, xh, xl, sq, nidx);
  k_stats<<<1024, 256, 0, stream>>>(u, v, nidx, b, stats);
  k_out <<<1024, 256, 0, stream>>>(u, v, nidx, b, gamma, beta, stats, out);
}

// Round 5
// 430.899 us; speedup vs baseline: 11.8014x; 2.5014x over previous
//
#include <hip/hip_runtime.h>
#include <math.h>

#define B_EV    16
#define N_NODES 2048
#define K_NN    16
#define F_IN    64
#define L_OUT   64
#define NT      (B_EV * N_NODES)      // 32768
#define EDGES   (NT * K_NN)           // 524288

typedef __attribute__((ext_vector_type(8)))  short bh8;    // 8 bf16 = 4 VGPR
typedef __attribute__((ext_vector_type(16))) float f32x16; // MFMA acc

// ---------------- K0: per-node squared norms, bit-exact numpy pairwise fp32 ----------------
__global__ __launch_bounds__(256) void k_sq(const float* __restrict__ x,
                                            float* __restrict__ sq) {
  int tid = blockIdx.x * 256 + threadIdx.x;
  int node = tid >> 3;
  int j = tid & 7;
  const float* xr = x + (size_t)node * F_IN;
  float xv = xr[j];
  float s = __fmul_rn(xv, xv);
  #pragma unroll
  for (int i = 1; i < 8; ++i) {
    float c = xr[j + 8 * i];
    s = __fadd_rn(s, __fmul_rn(c, c));
  }
  s = __fadd_rn(s, __shfl_xor(s, 1));
  s = __fadd_rn(s, __shfl_xor(s, 2));
  s = __fadd_rn(s, __shfl_xor(s, 4));
  if (j == 0) sq[node] = s;
}

// ---------------- K0b: split x into bf16 hi/lo (x = hi + lo) ----------------
__device__ inline unsigned short bf16_rne(float f) {
  unsigned int u = __float_as_uint(f);
  return (unsigned short)((u + 0x7FFFu + ((u >> 16) & 1u)) >> 16);
}
__device__ inline float bf16f(unsigned short h) {
  return __uint_as_float(((unsigned int)h) << 16);
}
__global__ __launch_bounds__(256) void k_cvt(const float* __restrict__ x,
                                             unsigned short* __restrict__ xh,
                                             unsigned short* __restrict__ xl) {
  int i = blockIdx.x * 256 + threadIdx.x;
  float4 v = ((const float4*)x)[i];
  ushort4 h, l;
  h.x = bf16_rne(v.x); l.x = bf16_rne(v.x - bf16f(h.x));
  h.y = bf16_rne(v.y); l.y = bf16_rne(v.y - bf16f(h.y));
  h.z = bf16_rne(v.z); l.z = bf16_rne(v.z - bf16f(h.z));
  h.w = bf16_rne(v.w); l.w = bf16_rne(v.w - bf16f(h.w));
  ((ushort4*)xh)[i] = h;
  ((ushort4*)xl)[i] = l;
}

// ---------------- K1: u = x@(W1-W2), v = x@W2 ----------------
__global__ __launch_bounds__(256) void k_uv(const float* __restrict__ x,
                                            const float* __restrict__ W,
                                            float* __restrict__ u,
                                            float* __restrict__ v) {
  __shared__ float wd[64][65];
  __shared__ float w2[64][65];
  __shared__ float xs[16][64];
  for (int i = threadIdx.x; i < 4096; i += 256) {
    int f = i >> 6, l = i & 63;
    float w1v = W[i];
    float w2v = W[4096 + i];
    wd[f][l] = w1v - w2v;
    w2[f][l] = w2v;
  }
  int nodeBase = blockIdx.x * 16;
  for (int i = threadIdx.x; i < 1024; i += 256) {
    xs[i >> 6][i & 63] = x[(size_t)nodeBase * 64 + i];
  }
  __syncthreads();
  int l = threadIdx.x & 63, g = threadIdx.x >> 6;
  #pragma unroll
  for (int rep = 0; rep < 4; ++rep) {
    int n = g * 4 + rep;
    float au = 0.f, av = 0.f;
    #pragma unroll
    for (int f = 0; f < 64; ++f) {
      float xv = xs[n][f];
      au = fmaf(xv, wd[f][l], au);
      av = fmaf(xv, w2[f][l], av);
    }
    u[(size_t)(nodeBase + n) * 64 + l] = au;
    v[(size_t)(nodeBase + n) * 64 + l] = av;
  }
}

// ---------------- K2a: strip GEMM -> S (approx distances, fp32) ----------------
// Block: 32 rows of one event; 16 col-tiles of 128. MFMA (bf16 hi/lo, 3 passes)
// -> S-tile in LDS (stride 132, conflict-free) -> coalesced dump to global.
__global__ __launch_bounds__(256, 3) void k_gemm(const unsigned short* __restrict__ xh,
                                                 const unsigned short* __restrict__ xl,
                                                 const float* __restrict__ sq,
                                                 float* __restrict__ Sbuf,
                                                 int evBase) {
  __shared__ char  xb[32768];       // [0]=hi, [16384]=lo : [128 cols][64 feat] bf16, swizzled
  __shared__ float S[32 * 132];     // stride 132 (16B-aligned rows, ~2-way max)
  const int t    = threadIdx.x;
  const int w    = t >> 6;
  const int lane = t & 63;
  const int ev    = evBase + (blockIdx.x >> 6);
  const int strip = blockIdx.x & 63;
  const int rowBase = strip * 32;
  const size_t evNode = (size_t)ev * N_NODES;
  const float* __restrict__ sqev = sq + evNode;
  float* __restrict__ Sev = Sbuf + (size_t)(ev - evBase) * N_NODES * N_NODES;

  // stage A (32 strip rows, hi+lo), load A-frags
  {
    int col = t >> 3;
    int fb  = (t & 7) << 4;
    const char* gh = (const char*)(xh + (evNode + rowBase + col) * 64) + fb;
    const char* gl = (const char*)(xl + (evNode + rowBase + col) * 64) + fb;
    int off = (col * 128 + fb) ^ ((col & 7) << 4);
    *(uint4*)(xb + off)         = *(const uint4*)gh;
    *(uint4*)(xb + 16384 + off) = *(const uint4*)gl;
  }
  __syncthreads();
  bh8 ah[4], al[4];
  {
    int row = lane & 31;
    int fb  = (lane >> 5) * 16;
    #pragma unroll
    for (int ks = 0; ks < 4; ++ks) {
      int off = (row * 128 + ks * 32 + fb) ^ ((row & 7) << 4);
      ah[ks] = *(const bh8*)(xb + off);
      al[ks] = *(const bh8*)(xb + 16384 + off);
    }
  }

  for (int T = 0; T < 16; ++T) {
    __syncthreads();
    const int tileCol = T * 128;
    // stage B tile (128 cols, hi+lo)
    #pragma unroll
    for (int p = 0; p < 8; ++p) {
      int idx16 = (p & 3) * 256 + t;
      int col = idx16 >> 3;
      int fb  = (idx16 & 7) << 4;
      const unsigned short* src = (p < 4) ? xh : xl;
      const char* g = (const char*)(src + (evNode + tileCol + col) * 64) + fb;
      int off = ((p < 4) ? 0 : 16384) + ((col * 128 + fb) ^ ((col & 7) << 4));
      *(uint4*)(xb + off) = *(const uint4*)g;
    }
    __syncthreads();
    // MFMA: wave w -> cols [w*32, w*32+32)
    {
      f32x16 acc;
      #pragma unroll
      for (int q = 0; q < 16; ++q) acc[q] = 0.f;
      int colIn = w * 32 + (lane & 31);
      int fb = (lane >> 5) * 16;
      #pragma unroll
      for (int ks = 0; ks < 4; ++ks) {
        int off = (colIn * 128 + ks * 32 + fb) ^ ((colIn & 7) << 4);
        bh8 bh = *(const bh8*)(xb + off);
        bh8 bl = *(const bh8*)(xb + 16384 + off);
        acc = __builtin_amdgcn_mfma_f32_32x32x16_bf16(ah[ks], bh, acc, 0, 0, 0);
        acc = __builtin_amdgcn_mfma_f32_32x32x16_bf16(ah[ks], bl, acc, 0, 0, 0);
        acc = __builtin_amdgcn_mfma_f32_32x32x16_bf16(al[ks], bh, acc, 0, 0, 0);
      }
      float sqc = sqev[tileCol + colIn];
      #pragma unroll
      for (int reg = 0; reg < 16; ++reg) {
        int m = (reg & 3) + 8 * (reg >> 2) + 4 * (lane >> 5);
        S[m * 132 + colIn] = fmaf(-2.0f, acc[reg], sqc);
      }
    }
    __syncthreads();
    // dump S tile, coalesced: thread t -> row r=t>>3, cols [cg*16, cg*16+16)
    {
      int r  = t >> 3;
      int cg = t & 7;
      float* gS = Sev + (size_t)(rowBase + r) * N_NODES + tileCol + cg * 16;
      const float* lS = S + r * 132 + cg * 16;
      #pragma unroll
      for (int j = 0; j < 4; ++j)
        *(float4*)(gS + j * 4) = *(const float4*)(lS + j * 4);
    }
  }
}

// ---------------- K2b: per-row selection (one wave per row, barrier-free) ----------------
// Pass1: lane-min of 32 S-values -> bitonic sort 64 lane-mins -> theta = 16th.
// Pass2: ballot-compact survivors (s <= theta+delta) into LDS.
// Rescore survivors exactly (numpy-fp32-emulated), 64-lane lexicographic
// bitonic sort on (s32, idx), keep top-16 (merging 64-chunks if needed).
#define SEL_CAP 448
#define SEL_DELTA 0.05f

__global__ __launch_bounds__(256, 4) void k_sel(const float* __restrict__ x,
                                                const float* __restrict__ sq,
                                                const float* __restrict__ Sbuf,
                                                int* __restrict__ nidx,
                                                int evBase) {
  __shared__ int candLDS[4][SEL_CAP];
  const int w    = threadIdx.x >> 6;
  const int lane = threadIdx.x & 63;
  const int rowInChunk = blockIdx.x * 4 + w;
  const int ev = evBase + (rowInChunk >> 11);
  const int rowInEv = rowInChunk & 2047;
  const size_t evNode = (size_t)ev * N_NODES;
  const float* __restrict__ Srow = Sbuf + (size_t)rowInChunk * N_NODES;
  const float* __restrict__ sqev = sq + evNode;

  // ---- pass 1: lane-min over 32 values (cols j*256 + lane*4 + e) ----
  float mn = 3.4e38f;
  #pragma unroll
  for (int j = 0; j < 8; ++j) {
    float4 f = *(const float4*)(Srow + j * 256 + lane * 4);
    mn = fminf(mn, fminf(fminf(f.x, f.y), fminf(f.z, f.w)));
  }
  // bitonic sort 64 lane-mins ascending (value only)
  #pragma unroll
  for (int k = 2; k <= 64; k <<= 1) {
    #pragma unroll
    for (int j = k >> 1; j >= 1; j >>= 1) {
      float o = __shfl_xor(mn, j);
      bool up = ((lane & k) == 0);
      bool iAmLower = ((lane & j) == 0);
      bool wantSmall = (up == iAmLower);
      bool less = (mn < o);
      if (less != wantSmall) mn = o;
    }
  }
  const float thr = __shfl(mn, 15) + SEL_DELTA;

  // ---- pass 2: ballot-compact survivors ----
  int base = 0;
  #pragma unroll
  for (int j = 0; j < 8; ++j) {
    float4 f = *(const float4*)(Srow + j * 256 + lane * 4);
    #pragma unroll
    for (int e = 0; e < 4; ++e) {
      float s = (e == 0) ? f.x : (e == 1) ? f.y : (e == 2) ? f.z : f.w;
      int col = j * 256 + lane * 4 + e;
      bool p = (s <= thr);
      unsigned long long mask = __ballot(p);
      if (p) {
        int pos = base + __popcll(mask & ((1ull << lane) - 1ull));
        if (pos < SEL_CAP) candLDS[w][pos] = col;
      }
      base += (int)__popcll(mask);
    }
  }
  const int cnt = (base < SEL_CAP) ? base : SEL_CAP;

  // ---- rescore + select ----
  float4 xi[16];
  {
    const float4* xr = (const float4*)(x + (evNode + rowInEv) * F_IN);
    #pragma unroll
    for (int fq = 0; fq < 16; ++fq) xi[fq] = xr[fq];
  }
  const float sqn = sqev[rowInEv];
  const float* __restrict__ xev = x + evNode * F_IN;

  float rv = 3.4e38f; int ri = 0x7FFFFFFF;   // running top-16 in lanes 0..15
  for (int b2 = 0; b2 < cnt; b2 += 64) {
    const int ci = b2 + lane;
    const bool act = (ci < cnt);
    int mcol = act ? candLDS[w][ci] : 0x7FFFFFFF;
    float sv = 3.4e38f;
    if (act) {
      const float4* xm = (const float4*)(xev + (size_t)mcol * F_IN);
      double dot = 0.0;
      #pragma unroll
      for (int fq = 0; fq < 16; ++fq) {
        float4 cc = xm[fq];
        dot = fma((double)xi[fq].x, (double)cc.x, dot);
        dot = fma((double)xi[fq].y, (double)cc.y, dot);
        dot = fma((double)xi[fq].z, (double)cc.z, dot);
        dot = fma((double)xi[fq].w, (double)cc.w, dot);
      }
      const float dot32 = (float)dot;
      sv = __fsub_rn(__fadd_rn(sqn, sqev[mcol]), __fmul_rn(2.0f, dot32));
    }
    // 64-lane lexicographic bitonic sort ascending on (sv, mcol)
    #pragma unroll
    for (int k = 2; k <= 64; k <<= 1) {
      #pragma unroll
      for (int j = k >> 1; j >= 1; j >>= 1) {
        float ov = __shfl_xor(sv, j);
        int   oi = __shfl_xor(mcol, j);
        bool up = ((lane & k) == 0);
        bool iAmLower = ((lane & j) == 0);
        bool wantSmall = (up == iAmLower);
        bool less = (sv < ov) || ((sv == ov) && (mcol < oi));
        if (less != wantSmall) { sv = ov; mcol = oi; }
      }
    }
    if (b2 == 0) {
      rv = sv; ri = mcol;          // lanes 0..15 hold chunk top-16 ascending
    } else {
      // merge running (lanes 0..15 asc) with chunk top-16 (reversed into 16..31)
      float mv = (lane < 16) ? rv : __shfl(sv, 31 - lane);
      int   mi = (lane < 16) ? ri : __shfl(mcol, 31 - lane);
      #pragma unroll
      for (int j = 16; j >= 1; j >>= 1) {
        float ov = __shfl_xor(mv, j);
        int   oi = __shfl_xor(mi, j);
        bool iAmLower = ((lane & j) == 0);
        bool less = (mv < ov) || ((mv == ov) && (mi < oi));
        if (less != iAmLower) { mv = ov; mi = oi; }
      }
      rv = mv; ri = mi;
    }
  }
  if (lane < 16)
    nidx[(evNode + rowInEv) * K_NN + lane] = (int)evNode + ri;
}

// ---------------- K2-fallback: fused kNN (round-4 validated path) ----------------
#define NS 16
#define NC 128
union KnnSmem {
  struct {
    char  xb[32768];
    float S[32 * 129];
  } a;
  struct {
    float sc[32][NC + 1];
    int   id[32][NC + 1];
    int   cand[32][24];
    float resc[32][24];
  } b;
};

__global__ __launch_bounds__(256, 3) void k_knn(const float* __restrict__ x,
                                                const unsigned short* __restrict__ xh,
                                                const unsigned short* __restrict__ xl,
                                                const float* __restrict__ sq,
                                                int* __restrict__ nidx) {
  __shared__ KnnSmem sm;
  const int t    = threadIdx.x;
  const int r    = t & 31;
  const int c8   = t >> 5;
  const int w    = t >> 6;
  const int lane = t & 63;
  const int ev    = blockIdx.x >> 6;
  const int strip = blockIdx.x & 63;
  const int rowBase = strip * 32;
  const size_t evNode = (size_t)ev * N_NODES;
  const float* __restrict__ sqev = sq + evNode;

  {
    int col = t >> 3;
    int fb  = (t & 7) << 4;
    const char* gh = (const char*)(xh + (evNode + rowBase + col) * 64) + fb;
    const char* gl = (const char*)(xl + (evNode + rowBase + col) * 64) + fb;
    int off = (col * 128 + fb) ^ ((col & 7) << 4);
    *(uint4*)(sm.a.xb + off)         = *(const uint4*)gh;
    *(uint4*)(sm.a.xb + 16384 + off) = *(const uint4*)gl;
  }
  __syncthreads();
  bh8 ah[4], al[4];
  {
    int row = lane & 31;
    int fb  = (lane >> 5) * 16;
    #pragma unroll
    for (int ks = 0; ks < 4; ++ks) {
      int off = (row * 128 + ks * 32 + fb) ^ ((row & 7) << 4);
      ah[ks] = *(const bh8*)(sm.a.xb + off);
      al[ks] = *(const bh8*)(sm.a.xb + 16384 + off);
    }
  }

  float dist[NS]; int idxk[NS];
  #pragma unroll
  for (int q = 0; q < NS; ++q) { dist[q] = 3.4e38f; idxk[q] = 0x7FFFFFFF; }
  float curMax = 3.4e38f;

  for (int T = 0; T < 16; ++T) {
    __syncthreads();
    const int tileCol = T * 128;
    #pragma unroll
    for (int p = 0; p < 8; ++p) {
      int idx16 = (p & 3) * 256 + t;
      int col = idx16 >> 3;
      int fb  = (idx16 & 7) << 4;
      const unsigned short* src = (p < 4) ? xh : xl;
      const char* g = (const char*)(src + (evNode + tileCol + col) * 64) + fb;
      int off = ((p < 4) ? 0 : 16384) + ((col * 128 + fb) ^ ((col & 7) << 4));
      *(uint4*)(sm.a.xb + off) = *(const uint4*)g;
    }
    __syncthreads();
    {
      f32x16 acc;
      #pragma unroll
      for (int q = 0; q < 16; ++q) acc[q] = 0.f;
      int colIn = w * 32 + (lane & 31);
      int fb = (lane >> 5) * 16;
      #pragma unroll
      for (int ks = 0; ks < 4; ++ks) {
        int off = (colIn * 128 + ks * 32 + fb) ^ ((colIn & 7) << 4);
        bh8 bh = *(const bh8*)(sm.a.xb + off);
        bh8 bl = *(const bh8*)(sm.a.xb + 16384 + off);
        acc = __builtin_amdgcn_mfma_f32_32x32x16_bf16(ah[ks], bh, acc, 0, 0, 0);
        acc = __builtin_amdgcn_mfma_f32_32x32x16_bf16(ah[ks], bl, acc, 0, 0, 0);
        acc = __builtin_amdgcn_mfma_f32_32x32x16_bf16(al[ks], bh, acc, 0, 0, 0);
      }
      float sqc = sqev[tileCol + colIn];
      #pragma unroll
      for (int reg = 0; reg < 16; ++reg) {
        int m = (reg & 3) + 8 * (reg >> 2) + 4 * (lane >> 5);
        sm.a.S[m * 129 + colIn] = fmaf(-2.0f, acc[reg], sqc);
      }
    }
    __syncthreads();
    for (int j = 0; j < 16; ++j) {
      int cIn = c8 * 16 + j;
      float s = sm.a.S[r * 129 + cIn];
      if (s <= curMax) {
        int col = tileCol + cIn;
        float bv = dist[0]; int bi = idxk[0]; int slot = 0;
        #pragma unroll
        for (int q = 1; q < NS; ++q) {
          bool worse = (dist[q] > bv) || ((dist[q] == bv) && (idxk[q] > bi));
          slot = worse ? q : slot;
          bv = worse ? dist[q] : bv;
          bi = worse ? idxk[q] : bi;
        }
        if ((s < bv) || ((s == bv) && (col < bi))) {
          #pragma unroll
          for (int q = 0; q < NS; ++q) {
            dist[q] = (q == slot) ? s : dist[q];
            idxk[q] = (q == slot) ? col : idxk[q];
          }
          float cm = dist[0];
          #pragma unroll
          for (int q = 1; q < NS; ++q) cm = fmaxf(cm, dist[q]);
          curMax = cm;
        }
      }
    }
  }

  __syncthreads();
  #pragma unroll
  for (int q = 0; q < NS; ++q) {
    sm.b.sc[r][c8 * NS + q] = dist[q];
    sm.b.id[r][c8 * NS + q] = idxk[q];
  }
  __syncthreads();

  if (t < 32) {
    float dd[24]; int di[24];
    #pragma unroll
    for (int q = 0; q < 24; ++q) { dd[q] = 3.4e38f; di[q] = 0x7FFFFFFF; }
    for (int c = 0; c < NC; ++c) {
      float s = sm.b.sc[t][c];
      int m = sm.b.id[t][c];
      float bv = dd[0]; int bi = di[0]; int slot = 0;
      #pragma unroll
      for (int q = 1; q < 24; ++q) {
        bool worse = (dd[q] > bv) || ((dd[q] == bv) && (di[q] > bi));
        slot = worse ? q : slot;
        bv = worse ? dd[q] : bv;
        bi = worse ? di[q] : bi;
      }
      if ((s < bv) || ((s == bv) && (m < bi))) {
        #pragma unroll
        for (int q = 0; q < 24; ++q) {
          dd[q] = (q == slot) ? s : dd[q];
          di[q] = (q == slot) ? m : di[q];
        }
      }
    }
    #pragma unroll
    for (int q = 0; q < 24; ++q) sm.b.cand[t][q] = di[q];
  }
  __syncthreads();

  {
    float4 xi[16];
    const float4* xr = (const float4*)(x + (evNode + rowBase + r) * F_IN);
    #pragma unroll
    for (int fq = 0; fq < 16; ++fq) xi[fq] = xr[fq];
    const float sqn = sqev[rowBase + r];
    const float* __restrict__ xev = x + evNode * F_IN;
    #pragma unroll
    for (int ii = 0; ii < 3; ++ii) {
      int i = c8 + ii * 8;
      int m = sm.b.cand[r][i];
      const float4* xm = (const float4*)(xev + (size_t)m * F_IN);
      double dot = 0.0;
      #pragma unroll
      for (int fq = 0; fq < 16; ++fq) {
        float4 cc = xm[fq];
        dot = fma((double)xi[fq].x, (double)cc.x, dot);
        dot = fma((double)xi[fq].y, (double)cc.y, dot);
        dot = fma((double)xi[fq].z, (double)cc.z, dot);
        dot = fma((double)xi[fq].w, (double)cc.w, dot);
      }
      const float dot32 = (float)dot;
      sm.b.resc[r][i] = __fsub_rn(__fadd_rn(sqn, sqev[m]),
                                  __fmul_rn(2.0f, dot32));
    }
  }
  __syncthreads();

  if (t < 32) {
    float dd[K_NN]; int di[K_NN];
    #pragma unroll
    for (int q = 0; q < K_NN; ++q) { dd[q] = 3.4e38f; di[q] = 0x7FFFFFFF; }
    for (int c = 0; c < 24; ++c) {
      float s = sm.b.resc[t][c];
      int m = sm.b.cand[t][c];
      float bv = dd[0]; int bi = di[0]; int slot = 0;
      #pragma unroll
      for (int q = 1; q < K_NN; ++q) {
        bool worse = (dd[q] > bv) || ((dd[q] == bv) && (di[q] > bi));
        slot = worse ? q : slot;
        bv = worse ? dd[q] : bv;
        bi = worse ? di[q] : bi;
      }
      if ((s < bv) || ((s == bv) && (m < bi))) {
        #pragma unroll
        for (int q = 0; q < K_NN; ++q) {
          dd[q] = (q == slot) ? s : dd[q];
          di[q] = (q == slot) ? m : di[q];
        }
      }
    }
    const size_t row = evNode + rowBase + t;
    #pragma unroll
    for (int q = 0; q < K_NN; ++q)
      nidx[row * K_NN + q] = (int)evNode + di[q];
  }
}

// ---------------- K3: BN statistics over all edges ----------------
#define NB3 32
__global__ __launch_bounds__(256) void k_stats(const float* __restrict__ u,
                                               const float* __restrict__ v,
                                               const int* __restrict__ nidx,
                                               const float* __restrict__ bvec,
                                               float* __restrict__ stats) {
  __shared__ float red1[4][64];
  __shared__ float red2[4][64];
  const int l = threadIdx.x & 63, g = threadIdx.x >> 6;
  const int base = blockIdx.x * NB3;
  const float bl = bvec[l];
  float s1 = 0.f, s2 = 0.f;
  for (int nn = g; nn < NB3; nn += 4) {
    const int node = base + nn;
    const float ui = u[(size_t)node * 64 + l] + bl;
    const int* ip = nidx + (size_t)node * K_NN;
    #pragma unroll
    for (int k = 0; k < K_NN; ++k) {
      const float vj = v[(size_t)ip[k] * 64 + l];
      const float h = ui + vj;
      s1 += h;
      s2 = fmaf(h, h, s2);
    }
  }
  red1[g][l] = s1; red2[g][l] = s2;
  __syncthreads();
  if (g == 0) {
    float t1 = red1[0][l] + red1[1][l] + red1[2][l] + red1[3][l];
    float t2 = red2[0][l] + red2[1][l] + red2[2][l] + red2[3][l];
    atomicAdd(&stats[l], t1);
    atomicAdd(&stats[64 + l], t2);
  }
}

// ---------------- K4: normalize + relu + mean over K ----------------
__global__ __launch_bounds__(256) void k_out(const float* __restrict__ u,
                                             const float* __restrict__ v,
                                             const int* __restrict__ nidx,
                                             const float* __restrict__ bvec,
                                             const float* __restrict__ gamma,
                                             const float* __restrict__ beta,
                                             const float* __restrict__ stats,
                                             float* __restrict__ out) {
  const int l = threadIdx.x & 63, g = threadIdx.x >> 6;
  const float inv = 1.0f / (float)EDGES;
  const float mean = stats[l] * inv;
  const float ex2 = stats[64 + l] * inv;
  const float var = ex2 - mean * mean;
  const float a = gamma[l] * rsqrtf(var + 1e-5f);
  const float bb = fmaf(-mean, a, beta[l]);
  const float bl = bvec[l];
  const int base = blockIdx.x * NB3;
  for (int nn = g; nn < NB3; nn += 4) {
    const int node = base + nn;
    const float ui = u[(size_t)node * 64 + l] + bl;
    const int* ip = nidx + (size_t)node * K_NN;
    float acc = 0.f;
    #pragma unroll
    for (int k = 0; k < K_NN; ++k) {
      const float vj = v[(size_t)ip[k] * 64 + l];
      const float h = ui + vj;
      acc += fmaxf(fmaf(a, h, bb), 0.f);
    }
    out[(size_t)node * 64 + l] = acc * (1.0f / 16.0f);
  }
}

// ---------------- launcher ----------------
extern "C" void kernel_launch(void* const* d_in, const int* in_sizes, int n_in,
                              void* d_out, int out_size, void* d_ws, size_t ws_size,
                              hipStream_t stream) {
  (void)in_sizes; (void)n_in; (void)out_size;
  const float* x     = (const float*)d_in[0];
  const float* W     = (const float*)d_in[2];
  const float* b     = (const float*)d_in[3];
  const float* gamma = (const float*)d_in[4];
  const float* beta  = (const float*)d_in[5];
  float* out = (float*)d_out;

  char* ws = (char*)d_ws;
  float*          u     = (float*)(ws);                    //  8 MB
  float*          v     = (float*)(ws + 8388608);          //  8 MB
  float*          sq    = (float*)(ws + 16777216);         //  128 KB
  int*            nidx  = (int*)  (ws + 16908288);         //  2 MB
  float*          stats = (float*)(ws + 19005440);         //  512 B
  unsigned short* xh    = (unsigned short*)(ws + 19005952);//  4 MB
  unsigned short* xl    = (unsigned short*)(ws + 23200256);//  4 MB
  float*          Sbuf  = (float*)(ws + 27394560);         //  up to 256 MB

  const size_t sChunkBytes = (size_t)N_NODES * N_NODES * 4; // 16.8 MB per event
  size_t avail = (ws_size > 27394560) ? ws_size - 27394560 : 0;
  int evCap = (int)((avail / sChunkBytes < 16) ? (avail / sChunkBytes) : 16);

  hipMemsetAsync(stats, 0, 512, stream);
  k_sq  <<<1024, 256, 0, stream>>>(x, sq);
  k_cvt <<<2048, 256, 0, stream>>>(x, xh, xl);
  k_uv  <<<2048, 256, 0, stream>>>(x, W, u, v);

  if (evCap >= 1) {
    for (int e0 = 0; e0 < B_EV; e0 += evCap) {
      int ne = (B_EV - e0 < evCap) ? (B_EV - e0) : evCap;
      k_gemm<<<ne * 64, 256, 0, stream>>>(xh, xl, sq, Sbuf, e0);
      k_sel <<<ne * 512, 256, 0, stream>>>(x, sq, Sbuf, nidx, e0);
    }
  } else {
    k_knn<<<1024, 256, 0, stream>>>(x, xh, xl, sq, nidx);
  }

  k_stats<<<1024, 256, 0, stream>>>(u, v, nidx, b, stats);
  k_out <<<1024, 256, 0, stream>>>(u, v, nidx, b, gamma, beta, stats, out);
}

// Round 6
// 243.926 us; speedup vs baseline: 20.8474x; 1.7665x over previous
//
#include <hip/hip_runtime.h>
#include <math.h>

#define B_EV    16
#define N_NODES 2048
#define K_NN    16
#define F_IN    64
#define L_OUT   64
#define NT      (B_EV * N_NODES)      // 32768
#define EDGES   (NT * K_NN)           // 524288

typedef __attribute__((ext_vector_type(8)))  short bh8;    // 8 bf16 = 4 VGPR
typedef __attribute__((ext_vector_type(16))) float f32x16; // MFMA acc
typedef __attribute__((ext_vector_type(8)))  unsigned short us8;

// ---------------- K0: per-node squared norms, bit-exact numpy pairwise fp32 ----------------
__global__ __launch_bounds__(256) void k_sq(const float* __restrict__ x,
                                            float* __restrict__ sq) {
  int tid = blockIdx.x * 256 + threadIdx.x;
  int node = tid >> 3;
  int j = tid & 7;
  const float* xr = x + (size_t)node * F_IN;
  float xv = xr[j];
  float s = __fmul_rn(xv, xv);
  #pragma unroll
  for (int i = 1; i < 8; ++i) {
    float c = xr[j + 8 * i];
    s = __fadd_rn(s, __fmul_rn(c, c));
  }
  s = __fadd_rn(s, __shfl_xor(s, 1));
  s = __fadd_rn(s, __shfl_xor(s, 2));
  s = __fadd_rn(s, __shfl_xor(s, 4));
  if (j == 0) sq[node] = s;
}

// ---------------- K0b: split x into bf16 hi/lo (x = hi + lo) ----------------
__device__ inline unsigned short bf16_rne(float f) {
  unsigned int u = __float_as_uint(f);
  return (unsigned short)((u + 0x7FFFu + ((u >> 16) & 1u)) >> 16);
}
__device__ inline float bf16f(unsigned short h) {
  return __uint_as_float(((unsigned int)h) << 16);
}
__global__ __launch_bounds__(256) void k_cvt(const float* __restrict__ x,
                                             unsigned short* __restrict__ xh,
                                             unsigned short* __restrict__ xl) {
  int i = blockIdx.x * 256 + threadIdx.x;
  float4 v = ((const float4*)x)[i];
  ushort4 h, l;
  h.x = bf16_rne(v.x); l.x = bf16_rne(v.x - bf16f(h.x));
  h.y = bf16_rne(v.y); l.y = bf16_rne(v.y - bf16f(h.y));
  h.z = bf16_rne(v.z); l.z = bf16_rne(v.z - bf16f(h.z));
  h.w = bf16_rne(v.w); l.w = bf16_rne(v.w - bf16f(h.w));
  ((ushort4*)xh)[i] = h;
  ((ushort4*)xl)[i] = l;
}

// ---------------- K1: u = x@(W1-W2), v = x@W2 ----------------
__global__ __launch_bounds__(256) void k_uv(const float* __restrict__ x,
                                            const float* __restrict__ W,
                                            float* __restrict__ u,
                                            float* __restrict__ v) {
  __shared__ float wd[64][65];
  __shared__ float w2[64][65];
  __shared__ float xs[16][64];
  for (int i = threadIdx.x; i < 4096; i += 256) {
    int f = i >> 6, l = i & 63;
    float w1v = W[i];
    float w2v = W[4096 + i];
    wd[f][l] = w1v - w2v;
    w2[f][l] = w2v;
  }
  int nodeBase = blockIdx.x * 16;
  for (int i = threadIdx.x; i < 1024; i += 256) {
    xs[i >> 6][i & 63] = x[(size_t)nodeBase * 64 + i];
  }
  __syncthreads();
  int l = threadIdx.x & 63, g = threadIdx.x >> 6;
  #pragma unroll
  for (int rep = 0; rep < 4; ++rep) {
    int n = g * 4 + rep;
    float au = 0.f, av = 0.f;
    #pragma unroll
    for (int f = 0; f < 64; ++f) {
      float xv = xs[n][f];
      au = fmaf(xv, wd[f][l], au);
      av = fmaf(xv, w2[f][l], av);
    }
    u[(size_t)(nodeBase + n) * 64 + l] = au;
    v[(size_t)(nodeBase + n) * 64 + l] = av;
  }
}

// ---------------- K2a: strip GEMM -> S (bf16 screening distances) ----------------
// hh-only MFMA (screening precision; exact rescore happens in k_sel).
// Block: 32 rows of one event; 16 col-tiles of 128. S-tile LDS (f32, stride 132)
// -> bf16-pack -> coalesced dump.
__global__ __launch_bounds__(256, 3) void k_gemm(const unsigned short* __restrict__ xh,
                                                 const float* __restrict__ sq,
                                                 unsigned short* __restrict__ Sbuf,
                                                 int evBase) {
  __shared__ char  xb[16384];       // hi tile: [128 cols][64 feat] bf16, swizzled
  __shared__ float S[32 * 132];
  const int t    = threadIdx.x;
  const int w    = t >> 6;
  const int lane = t & 63;
  const int ev    = evBase + (blockIdx.x >> 6);
  const int strip = blockIdx.x & 63;
  const int rowBase = strip * 32;
  const size_t evNode = (size_t)ev * N_NODES;
  const float* __restrict__ sqev = sq + evNode;
  unsigned short* __restrict__ Sev =
      Sbuf + (size_t)(ev - evBase) * N_NODES * N_NODES;

  // stage A (32 strip rows, hi), load A-frags
  {
    int col = t >> 3;
    int fb  = (t & 7) << 4;
    const char* gh = (const char*)(xh + (evNode + rowBase + col) * 64) + fb;
    int off = (col * 128 + fb) ^ ((col & 7) << 4);
    *(uint4*)(xb + off) = *(const uint4*)gh;
  }
  __syncthreads();
  bh8 ah[4];
  {
    int row = lane & 31;
    int fb  = (lane >> 5) * 16;
    #pragma unroll
    for (int ks = 0; ks < 4; ++ks) {
      int off = (row * 128 + ks * 32 + fb) ^ ((row & 7) << 4);
      ah[ks] = *(const bh8*)(xb + off);
    }
  }

  for (int T = 0; T < 16; ++T) {
    __syncthreads();
    const int tileCol = T * 128;
    // stage B tile (128 cols, hi)
    #pragma unroll
    for (int p = 0; p < 4; ++p) {
      int idx16 = p * 256 + t;
      int col = idx16 >> 3;
      int fb  = (idx16 & 7) << 4;
      const char* g = (const char*)(xh + (evNode + tileCol + col) * 64) + fb;
      int off = (col * 128 + fb) ^ ((col & 7) << 4);
      *(uint4*)(xb + off) = *(const uint4*)g;
    }
    __syncthreads();
    // MFMA: wave w -> cols [w*32, w*32+32)
    {
      f32x16 acc;
      #pragma unroll
      for (int q = 0; q < 16; ++q) acc[q] = 0.f;
      int colIn = w * 32 + (lane & 31);
      int fb = (lane >> 5) * 16;
      #pragma unroll
      for (int ks = 0; ks < 4; ++ks) {
        int off = (colIn * 128 + ks * 32 + fb) ^ ((colIn & 7) << 4);
        bh8 bh = *(const bh8*)(xb + off);
        acc = __builtin_amdgcn_mfma_f32_32x32x16_bf16(ah[ks], bh, acc, 0, 0, 0);
      }
      float sqc = sqev[tileCol + colIn];
      #pragma unroll
      for (int reg = 0; reg < 16; ++reg) {
        int m = (reg & 3) + 8 * (reg >> 2) + 4 * (lane >> 5);
        S[m * 132 + colIn] = fmaf(-2.0f, acc[reg], sqc);
      }
    }
    __syncthreads();
    // dump S tile as bf16, coalesced: thread -> row r=t>>3, 16 cols
    {
      int r  = t >> 3;
      int cg = t & 7;
      unsigned short* gS =
          Sev + (size_t)(rowBase + r) * N_NODES + tileCol + cg * 16;
      const float* lS = S + r * 132 + cg * 16;
      unsigned int wpk[8];
      #pragma unroll
      for (int j = 0; j < 8; ++j) {
        unsigned int lo = bf16_rne(lS[2 * j]);
        unsigned int hi = bf16_rne(lS[2 * j + 1]);
        wpk[j] = lo | (hi << 16);
      }
      uint4 o0, o1;
      o0.x = wpk[0]; o0.y = wpk[1]; o0.z = wpk[2]; o0.w = wpk[3];
      o1.x = wpk[4]; o1.y = wpk[5]; o1.z = wpk[6]; o1.w = wpk[7];
      *(uint4*)gS = o0;
      *(uint4*)(gS + 8) = o1;
    }
  }
}

// ---------------- K2b: per-row selection (one wave per row, barrier-free) ----------------
// Pass1: lane-min of 32 bf16-S values -> bitonic sort 64 lane-mins -> thr = 16th + delta.
// Pass2: ballot-compact survivors. Exact numpy-fp32-emulated rescore, 64-lane
// lexicographic bitonic top-16 on (s32, idx).
// delta: |s_bf16 - s_exact| <= ~0.85 (hh-only MFMA ~0.32 + bf16 quant ~0.5);
// superset argument needs 2x => 1.7. Use 3.0.
#define SEL_CAP 448
#define SEL_DELTA 3.0f

__global__ __launch_bounds__(256, 1) void k_sel(const float* __restrict__ x,
                                                const float* __restrict__ sq,
                                                const unsigned short* __restrict__ Sbuf,
                                                int* __restrict__ nidx,
                                                int evBase) {
  __shared__ int candLDS[4][SEL_CAP];
  const int w    = threadIdx.x >> 6;
  const int lane = threadIdx.x & 63;
  const int rowInChunk = blockIdx.x * 4 + w;
  const int ev = evBase + (rowInChunk >> 11);
  const int rowInEv = rowInChunk & 2047;
  const size_t evNode = (size_t)ev * N_NODES;
  const unsigned short* __restrict__ Srow =
      Sbuf + (size_t)rowInChunk * N_NODES;
  const float* __restrict__ sqev = sq + evNode;

  // ---- pass 1: load 32 consecutive cols per lane, lane-min ----
  float vals[32];
  #pragma unroll
  for (int q = 0; q < 4; ++q) {
    us8 vv = *(const us8*)(Srow + lane * 32 + q * 8);
    #pragma unroll
    for (int e = 0; e < 8; ++e)
      vals[q * 8 + e] = __uint_as_float(((unsigned int)vv[e]) << 16);
  }
  float mn = vals[0];
  #pragma unroll
  for (int q = 1; q < 32; ++q) mn = fminf(mn, vals[q]);
  // bitonic sort 64 lane-mins ascending
  #pragma unroll
  for (int k = 2; k <= 64; k <<= 1) {
    #pragma unroll
    for (int j = k >> 1; j >= 1; j >>= 1) {
      float o = __shfl_xor(mn, j);
      bool up = ((lane & k) == 0);
      bool iAmLower = ((lane & j) == 0);
      bool wantSmall = (up == iAmLower);
      bool less = (mn < o);
      if (less != wantSmall) mn = o;
    }
  }
  const float thr = __shfl(mn, 15) + SEL_DELTA;

  // ---- pass 2: ballot-compact survivors ----
  int base = 0;
  #pragma unroll
  for (int e = 0; e < 32; ++e) {
    bool p = (vals[e] <= thr);
    unsigned long long mask = __ballot(p);
    if (p) {
      int pos = base + __popcll(mask & ((1ull << lane) - 1ull));
      if (pos < SEL_CAP) candLDS[w][pos] = lane * 32 + e;
    }
    base += (int)__popcll(mask);
  }
  const int cnt = (base < SEL_CAP) ? base : SEL_CAP;

  // ---- exact rescore + select ----
  float4 xi[16];
  {
    const float4* xr = (const float4*)(x + (evNode + rowInEv) * F_IN);
    #pragma unroll
    for (int fq = 0; fq < 16; ++fq) xi[fq] = xr[fq];
  }
  const float sqn = sqev[rowInEv];
  const float* __restrict__ xev = x + evNode * F_IN;

  float rv = 3.4e38f; int ri = 0x7FFFFFFF;
  for (int b2 = 0; b2 < cnt; b2 += 64) {
    const int ci = b2 + lane;
    const bool act = (ci < cnt);
    int mcol = act ? candLDS[w][ci] : 0x7FFFFFFF;
    float sv = 3.4e38f;
    if (act) {
      const float4* xm = (const float4*)(xev + (size_t)mcol * F_IN);
      double dot = 0.0;
      #pragma unroll
      for (int fq = 0; fq < 16; ++fq) {
        float4 cc = xm[fq];
        dot = fma((double)xi[fq].x, (double)cc.x, dot);
        dot = fma((double)xi[fq].y, (double)cc.y, dot);
        dot = fma((double)xi[fq].z, (double)cc.z, dot);
        dot = fma((double)xi[fq].w, (double)cc.w, dot);
      }
      const float dot32 = (float)dot;
      sv = __fsub_rn(__fadd_rn(sqn, sqev[mcol]), __fmul_rn(2.0f, dot32));
    }
    // 64-lane lexicographic bitonic sort ascending on (sv, mcol)
    #pragma unroll
    for (int k = 2; k <= 64; k <<= 1) {
      #pragma unroll
      for (int j = k >> 1; j >= 1; j >>= 1) {
        float ov = __shfl_xor(sv, j);
        int   oi = __shfl_xor(mcol, j);
        bool up = ((lane & k) == 0);
        bool iAmLower = ((lane & j) == 0);
        bool wantSmall = (up == iAmLower);
        bool less = (sv < ov) || ((sv == ov) && (mcol < oi));
        if (less != wantSmall) { sv = ov; mcol = oi; }
      }
    }
    if (b2 == 0) {
      rv = sv; ri = mcol;
    } else {
      float mv = (lane < 16) ? rv : __shfl(sv, 31 - lane);
      int   mi = (lane < 16) ? ri : __shfl(mcol, 31 - lane);
      #pragma unroll
      for (int j = 16; j >= 1; j >>= 1) {
        float ov = __shfl_xor(mv, j);
        int   oi = __shfl_xor(mi, j);
        bool iAmLower = ((lane & j) == 0);
        bool less = (mv < ov) || ((mv == ov) && (mi < oi));
        if (less != iAmLower) { mv = ov; mi = oi; }
      }
      rv = mv; ri = mi;
    }
  }
  if (lane < 16)
    nidx[(evNode + rowInEv) * K_NN + lane] = (int)evNode + ri;
}

// ---------------- K2-fallback: fused kNN (round-4 validated path) ----------------
#define NS 16
#define NC 128
union KnnSmem {
  struct {
    char  xb[32768];
    float S[32 * 129];
  } a;
  struct {
    float sc[32][NC + 1];
    int   id[32][NC + 1];
    int   cand[32][24];
    float resc[32][24];
  } b;
};

__global__ __launch_bounds__(256, 3) void k_knn(const float* __restrict__ x,
                                                const unsigned short* __restrict__ xh,
                                                const unsigned short* __restrict__ xl,
                                                const float* __restrict__ sq,
                                                int* __restrict__ nidx) {
  __shared__ KnnSmem sm;
  const int t    = threadIdx.x;
  const int r    = t & 31;
  const int c8   = t >> 5;
  const int w    = t >> 6;
  const int lane = t & 63;
  const int ev    = blockIdx.x >> 6;
  const int strip = blockIdx.x & 63;
  const int rowBase = strip * 32;
  const size_t evNode = (size_t)ev * N_NODES;
  const float* __restrict__ sqev = sq + evNode;

  {
    int col = t >> 3;
    int fb  = (t & 7) << 4;
    const char* gh = (const char*)(xh + (evNode + rowBase + col) * 64) + fb;
    const char* gl = (const char*)(xl + (evNode + rowBase + col) * 64) + fb;
    int off = (col * 128 + fb) ^ ((col & 7) << 4);
    *(uint4*)(sm.a.xb + off)         = *(const uint4*)gh;
    *(uint4*)(sm.a.xb + 16384 + off) = *(const uint4*)gl;
  }
  __syncthreads();
  bh8 ah[4], al[4];
  {
    int row = lane & 31;
    int fb  = (lane >> 5) * 16;
    #pragma unroll
    for (int ks = 0; ks < 4; ++ks) {
      int off = (row * 128 + ks * 32 + fb) ^ ((row & 7) << 4);
      ah[ks] = *(const bh8*)(sm.a.xb + off);
      al[ks] = *(const bh8*)(sm.a.xb + 16384 + off);
    }
  }

  float dist[NS]; int idxk[NS];
  #pragma unroll
  for (int q = 0; q < NS; ++q) { dist[q] = 3.4e38f; idxk[q] = 0x7FFFFFFF; }
  float curMax = 3.4e38f;

  for (int T = 0; T < 16; ++T) {
    __syncthreads();
    const int tileCol = T * 128;
    #pragma unroll
    for (int p = 0; p < 8; ++p) {
      int idx16 = (p & 3) * 256 + t;
      int col = idx16 >> 3;
      int fb  = (idx16 & 7) << 4;
      const unsigned short* src = (p < 4) ? xh : xl;
      const char* g = (const char*)(src + (evNode + tileCol + col) * 64) + fb;
      int off = ((p < 4) ? 0 : 16384) + ((col * 128 + fb) ^ ((col & 7) << 4));
      *(uint4*)(sm.a.xb + off) = *(const uint4*)g;
    }
    __syncthreads();
    {
      f32x16 acc;
      #pragma unroll
      for (int q = 0; q < 16; ++q) acc[q] = 0.f;
      int colIn = w * 32 + (lane & 31);
      int fb = (lane >> 5) * 16;
      #pragma unroll
      for (int ks = 0; ks < 4; ++ks) {
        int off = (colIn * 128 + ks * 32 + fb) ^ ((colIn & 7) << 4);
        bh8 bh = *(const bh8*)(sm.a.xb + off);
        bh8 bl = *(const bh8*)(sm.a.xb + 16384 + off);
        acc = __builtin_amdgcn_mfma_f32_32x32x16_bf16(ah[ks], bh, acc, 0, 0, 0);
        acc = __builtin_amdgcn_mfma_f32_32x32x16_bf16(ah[ks], bl, acc, 0, 0, 0);
        acc = __builtin_amdgcn_mfma_f32_32x32x16_bf16(al[ks], bh, acc, 0, 0, 0);
      }
      float sqc = sqev[tileCol + colIn];
      #pragma unroll
      for (int reg = 0; reg < 16; ++reg) {
        int m = (reg & 3) + 8 * (reg >> 2) + 4 * (lane >> 5);
        sm.a.S[m * 129 + colIn] = fmaf(-2.0f, acc[reg], sqc);
      }
    }
    __syncthreads();
    for (int j = 0; j < 16; ++j) {
      int cIn = c8 * 16 + j;
      float s = sm.a.S[r * 129 + cIn];
      if (s <= curMax) {
        int col = tileCol + cIn;
        float bv = dist[0]; int bi = idxk[0]; int slot = 0;
        #pragma unroll
        for (int q = 1; q < NS; ++q) {
          bool worse = (dist[q] > bv) || ((dist[q] == bv) && (idxk[q] > bi));
          slot = worse ? q : slot;
          bv = worse ? dist[q] : bv;
          bi = worse ? idxk[q] : bi;
        }
        if ((s < bv) || ((s == bv) && (col < bi))) {
          #pragma unroll
          for (int q = 0; q < NS; ++q) {
            dist[q] = (q == slot) ? s : dist[q];
            idxk[q] = (q == slot) ? col : idxk[q];
          }
          float cm = dist[0];
          #pragma unroll
          for (int q = 1; q < NS; ++q) cm = fmaxf(cm, dist[q]);
          curMax = cm;
        }
      }
    }
  }

  __syncthreads();
  #pragma unroll
  for (int q = 0; q < NS; ++q) {
    sm.b.sc[r][c8 * NS + q] = dist[q];
    sm.b.id[r][c8 * NS + q] = idxk[q];
  }
  __syncthreads();

  if (t < 32) {
    float dd[24]; int di[24];
    #pragma unroll
    for (int q = 0; q < 24; ++q) { dd[q] = 3.4e38f; di[q] = 0x7FFFFFFF; }
    for (int c = 0; c < NC; ++c) {
      float s = sm.b.sc[t][c];
      int m = sm.b.id[t][c];
      float bv = dd[0]; int bi = di[0]; int slot = 0;
      #pragma unroll
      for (int q = 1; q < 24; ++q) {
        bool worse = (dd[q] > bv) || ((dd[q] == bv) && (di[q] > bi));
        slot = worse ? q : slot;
        bv = worse ? dd[q] : bv;
        bi = worse ? di[q] : bi;
      }
      if ((s < bv) || ((s == bv) && (m < bi))) {
        #pragma unroll
        for (int q = 0; q < 24; ++q) {
          dd[q] = (q == slot) ? s : dd[q];
          di[q] = (q == slot) ? m : di[q];
        }
      }
    }
    #pragma unroll
    for (int q = 0; q < 24; ++q) sm.b.cand[t][q] = di[q];
  }
  __syncthreads();

  {
    float4 xi[16];
    const float4* xr = (const float4*)(x + (evNode + rowBase + r) * F_IN);
    #pragma unroll
    for (int fq = 0; fq < 16; ++fq) xi[fq] = xr[fq];
    const float sqn = sqev[rowBase + r];
    const float* __restrict__ xev = x + evNode * F_IN;
    #pragma unroll
    for (int ii = 0; ii < 3; ++ii) {
      int i = c8 + ii * 8;
      int m = sm.b.cand[r][i];
      const float4* xm = (const float4*)(xev + (size_t)m * F_IN);
      double dot = 0.0;
      #pragma unroll
      for (int fq = 0; fq < 16; ++fq) {
        float4 cc = xm[fq];
        dot = fma((double)xi[fq].x, (double)cc.x, dot);
        dot = fma((double)xi[fq].y, (double)cc.y, dot);
        dot = fma((double)xi[fq].z, (double)cc.z, dot);
        dot = fma((double)xi[fq].w, (double)cc.w, dot);
      }
      const float dot32 = (float)dot;
      sm.b.resc[r][i] = __fsub_rn(__fadd_rn(sqn, sqev[m]),
                                  __fmul_rn(2.0f, dot32));
    }
  }
  __syncthreads();

  if (t < 32) {
    float dd[K_NN]; int di[K_NN];
    #pragma unroll
    for (int q = 0; q < K_NN; ++q) { dd[q] = 3.4e38f; di[q] = 0x7FFFFFFF; }
    for (int c = 0; c < 24; ++c) {
      float s = sm.b.resc[t][c];
      int m = sm.b.cand[t][c];
      float bv = dd[0]; int bi = di[0]; int slot = 0;
      #pragma unroll
      for (int q = 1; q < K_NN; ++q) {
        bool worse = (dd[q] > bv) || ((dd[q] == bv) && (di[q] > bi));
        slot = worse ? q : slot;
        bv = worse ? dd[q] : bv;
        bi = worse ? di[q] : bi;
      }
      if ((s < bv) || ((s == bv) && (m < bi))) {
        #pragma unroll
        for (int q = 0; q < K_NN; ++q) {
          dd[q] = (q == slot) ? s : dd[q];
          di[q] = (q == slot) ? m : di[q];
        }
      }
    }
    const size_t row = evNode + rowBase + t;
    #pragma unroll
    for (int q = 0; q < K_NN; ++q)
      nidx[row * K_NN + q] = (int)evNode + di[q];
  }
}

// ---------------- K3: BN statistics over all edges ----------------
#define NB3 32
__global__ __launch_bounds__(256) void k_stats(const float* __restrict__ u,
                                               const float* __restrict__ v,
                                               const int* __restrict__ nidx,
                                               const float* __restrict__ bvec,
                                               float* __restrict__ stats) {
  __shared__ float red1[4][64];
  __shared__ float red2[4][64];
  const int l = threadIdx.x & 63, g = threadIdx.x >> 6;
  const int base = blockIdx.x * NB3;
  const float bl = bvec[l];
  float s1 = 0.f, s2 = 0.f;
  for (int nn = g; nn < NB3; nn += 4) {
    const int node = base + nn;
    const float ui = u[(size_t)node * 64 + l] + bl;
    const int* ip = nidx + (size_t)node * K_NN;
    #pragma unroll
    for (int k = 0; k < K_NN; ++k) {
      const float vj = v[(size_t)ip[k] * 64 + l];
      const float h = ui + vj;
      s1 += h;
      s2 = fmaf(h, h, s2);
    }
  }
  red1[g][l] = s1; red2[g][l] = s2;
  __syncthreads();
  if (g == 0) {
    float t1 = red1[0][l] + red1[1][l] + red1[2][l] + red1[3][l];
    float t2 = red2[0][l] + red2[1][l] + red2[2][l] + red2[3][l];
    atomicAdd(&stats[l], t1);
    atomicAdd(&stats[64 + l], t2);
  }
}

// ---------------- K4: normalize + relu + mean over K ----------------
__global__ __launch_bounds__(256) void k_out(const float* __restrict__ u,
                                             const float* __restrict__ v,
                                             const int* __restrict__ nidx,
                                             const float* __restrict__ bvec,
                                             const float* __restrict__ gamma,
                                             const float* __restrict__ beta,
                                             const float* __restrict__ stats,
                                             float* __restrict__ out) {
  const int l = threadIdx.x & 63, g = threadIdx.x >> 6;
  const float inv = 1.0f / (float)EDGES;
  const float mean = stats[l] * inv;
  const float ex2 = stats[64 + l] * inv;
  const float var = ex2 - mean * mean;
  const float a = gamma[l] * rsqrtf(var + 1e-5f);
  const float bb = fmaf(-mean, a, beta[l]);
  const float bl = bvec[l];
  const int base = blockIdx.x * NB3;
  for (int nn = g; nn < NB3; nn += 4) {
    const int node = base + nn;
    const float ui = u[(size_t)node * 64 + l] + bl;
    const int* ip = nidx + (size_t)node * K_NN;
    float acc = 0.f;
    #pragma unroll
    for (int k = 0; k < K_NN; ++k) {
      const float vj = v[(size_t)ip[k] * 64 + l];
      const float h = ui + vj;
      acc += fmaxf(fmaf(a, h, bb), 0.f);
    }
    out[(size_t)node * 64 + l] = acc * (1.0f / 16.0f);
  }
}

// ---------------- launcher ----------------
extern "C" void kernel_launch(void* const* d_in, const int* in_sizes, int n_in,
                              void* d_out, int out_size, void* d_ws, size_t ws_size,
                              hipStream_t stream) {
  (void)in_sizes; (void)n_in; (void)out_size;
  const float* x     = (const float*)d_in[0];
  const float* W     = (const float*)d_in[2];
  const float* b     = (const float*)d_in[3];
  const float* gamma = (const float*)d_in[4];
  const float* beta  = (const float*)d_in[5];
  float* out = (float*)d_out;

  char* ws = (char*)d_ws;
  float*          u     = (float*)(ws);                    //  8 MB
  float*          v     = (float*)(ws + 8388608);          //  8 MB
  float*          sq    = (float*)(ws + 16777216);         //  128 KB
  int*            nidx  = (int*)  (ws + 16908288);         //  2 MB
  float*          stats = (float*)(ws + 19005440);         //  512 B
  unsigned short* xh    = (unsigned short*)(ws + 19005952);//  4 MB
  unsigned short* xl    = (unsigned short*)(ws + 23200256);//  4 MB
  unsigned short* Sbuf  = (unsigned short*)(ws + 27394560);//  up to 134 MB

  const size_t sChunkBytes = (size_t)N_NODES * N_NODES * 2; // 8.4 MB per event
  size_t avail = (ws_size > 27394560) ? ws_size - 27394560 : 0;
  int evCap = (int)((avail / sChunkBytes < 16) ? (avail / sChunkBytes) : 16);

  hipMemsetAsync(stats, 0, 512, stream);
  k_sq  <<<1024, 256, 0, stream>>>(x, sq);
  k_cvt <<<2048, 256, 0, stream>>>(x, xh, xl);
  k_uv  <<<2048, 256, 0, stream>>>(x, W, u, v);

  if (evCap >= 1) {
    for (int e0 = 0; e0 < B_EV; e0 += evCap) {
      int ne = (B_EV - e0 < evCap) ? (B_EV - e0) : evCap;
      k_gemm<<<ne * 64, 256, 0, stream>>>(xh, sq, Sbuf, e0);
      k_sel <<<ne * 512, 256, 0, stream>>>(x, sq, Sbuf, nidx, e0);
    }
  } else {
    k_knn<<<1024, 256, 0, stream>>>(x, xh, xl, sq, nidx);
  }

  k_stats<<<1024, 256, 0, stream>>>(u, v, nidx, b, stats);
  k_out <<<1024, 256, 0, stream>>>(u, v, nidx, b, gamma, beta, stats, out);
}